// Round 3
// baseline (7812.889 us; speedup 1.0000x reference)
//
#include <hip/hip_runtime.h>
#include <cstdint>

// ---------------- dims ----------------
#define DD     768
#define NTOK   1024
#define SEQ    512
#define NHEAD  12
#define HDIM   64
#define VOCAB  50258
#define CAP    80
#define AUXOFF 51464192LL   // 2*512*50258

typedef short bf16x8 __attribute__((ext_vector_type(8)));
typedef float f32x4  __attribute__((ext_vector_type(4)));

// ---------------- threefry2x32 (exact JAX) ----------------
__host__ __device__ inline void threefry(uint32_t k0, uint32_t k1,
                                         uint32_t& x0, uint32_t& x1) {
  uint32_t ks0 = k0, ks1 = k1, ks2 = k0 ^ k1 ^ 0x1BD11BDAu;
  x0 += ks0; x1 += ks1;
#define RND(r) { x0 += x1; x1 = (x1 << (r)) | (x1 >> (32 - (r))); x1 ^= x0; }
  RND(13) RND(15) RND(26) RND(6)   x0 += ks1; x1 += ks2 + 1u;
  RND(17) RND(29) RND(16) RND(24)  x0 += ks2; x1 += ks0 + 2u;
  RND(13) RND(15) RND(26) RND(6)   x0 += ks0; x1 += ks1 + 3u;
  RND(17) RND(29) RND(16) RND(24)  x0 += ks1; x1 += ks2 + 4u;
  RND(13) RND(15) RND(26) RND(6)   x0 += ks2; x1 += ks0 + 5u;
#undef RND
}

__device__ inline unsigned short f2bf(float f) {
  union { float f; uint32_t u; } v; v.f = f;
  uint32_t u = v.u;
  return (unsigned short)((u + 0x7FFFu + ((u >> 16) & 1u)) >> 16);
}
__device__ inline float bf2f(unsigned short h) {
  union { uint32_t u; float f; } v; v.u = ((uint32_t)h) << 16; return v.f;
}
__device__ inline float gelu_tanh_f(float x) {
  float x3 = x * x * x;
  return 0.5f * x * (1.f + tanhf(0.7978845608028654f * (x + 0.044715f * x3)));
}
__device__ inline float gelu_erf_f(float x) {
  return 0.5f * x * (1.f + erff(x * 0.7071067811865476f));
}

// ---------------- GEMM (bf16x3 split for ~f32 accuracy) ----------------
// C = A @ B [+bias][+act][+resid]; A: MxK rm. B: KxN rm (TRANS_B=0) or NxK rm (1).
template<bool TRANS_B>
__global__ __launch_bounds__(256)
void k_gemm(const float* __restrict__ Ag, const float* __restrict__ Bg,
            float* __restrict__ Cg, const float* __restrict__ biasg,
            const float* __restrict__ residg,
            int M, int N, int K, int lda, int ldb, int ldc, int nh,
            long long sAb, long long sAh, long long sBb, long long sBh,
            long long sCb, long long sCh, long long sBias, int act)
{
  const int z  = blockIdx.z;
  const int zb = z / nh, zh = z - zb * nh;
  const float* A = Ag + zb * sAb + zh * sAh;
  const float* B = Bg + zb * sBb + zh * sBh;
  float*       C = Cg + zb * sCb + zh * sCh;
  const float* R = residg ? residg + zb * sCb + zh * sCh : nullptr;
  const float* bs = biasg ? biasg + (long long)z * sBias : nullptr;

  const int m0 = blockIdx.y * 64;
  const int n0 = blockIdx.x * 64;

  __shared__ __attribute__((aligned(16))) unsigned short sAh_[64][36];
  __shared__ __attribute__((aligned(16))) unsigned short sAl_[64][36];
  __shared__ __attribute__((aligned(16))) unsigned short sBh_[64][36];
  __shared__ __attribute__((aligned(16))) unsigned short sBl_[64][36];

  const int tid  = threadIdx.x;
  const int wave = tid >> 6;
  const int lane = tid & 63;
  const int l15  = lane & 15;
  const int kf   = (lane >> 4) * 8;

  f32x4 zf = {0.f, 0.f, 0.f, 0.f};
  f32x4 acc[4] = {zf, zf, zf, zf};

  const int ar = tid >> 2;         // 0..63
  const int ac = (tid & 3) * 8;    // 0,8,16,24

  for (int kk = 0; kk < K; kk += 32) {
    // stage A tile (64x32) split hi/lo
    {
      float v[8];
      if (m0 + ar < M) {
        const float* p = A + (long long)(m0 + ar) * lda + kk + ac;
        #pragma unroll
        for (int j = 0; j < 8; j++) v[j] = p[j];
      } else {
        #pragma unroll
        for (int j = 0; j < 8; j++) v[j] = 0.f;
      }
      #pragma unroll
      for (int j = 0; j < 8; j += 2) {
        unsigned short h0 = f2bf(v[j]), h1 = f2bf(v[j + 1]);
        float r0 = v[j] - bf2f(h0), r1 = v[j + 1] - bf2f(h1);
        *(uint32_t*)&sAh_[ar][ac + j] = (uint32_t)h0 | ((uint32_t)h1 << 16);
        *(uint32_t*)&sAl_[ar][ac + j] = (uint32_t)f2bf(r0) | ((uint32_t)f2bf(r1) << 16);
      }
    }
    // stage B tile into sB[n][k] split hi/lo
    if (TRANS_B) {
      float v[8];
      int nrow = n0 + ar;
      if (nrow < N) {
        const float* p = B + (long long)nrow * ldb + kk + ac;
        #pragma unroll
        for (int j = 0; j < 8; j++) v[j] = p[j];
      } else {
        #pragma unroll
        for (int j = 0; j < 8; j++) v[j] = 0.f;
      }
      #pragma unroll
      for (int j = 0; j < 8; j += 2) {
        unsigned short h0 = f2bf(v[j]), h1 = f2bf(v[j + 1]);
        float r0 = v[j] - bf2f(h0), r1 = v[j + 1] - bf2f(h1);
        *(uint32_t*)&sBh_[ar][ac + j] = (uint32_t)h0 | ((uint32_t)h1 << 16);
        *(uint32_t*)&sBl_[ar][ac + j] = (uint32_t)f2bf(r0) | ((uint32_t)f2bf(r1) << 16);
      }
    } else {
      int n = n0 + lane;
      bool ok = n < N;
      #pragma unroll
      for (int i = 0; i < 8; i++) {
        int k = (tid >> 6) + i * 4;
        float v = ok ? B[(long long)(kk + k) * ldb + n] : 0.f;
        unsigned short h = f2bf(v);
        sBh_[lane][k] = h;
        sBl_[lane][k] = f2bf(v - bf2f(h));
      }
    }
    __syncthreads();

    bf16x8 ah, al;
    {
      const uint32_t* ph = (const uint32_t*)&sAh_[wave * 16 + l15][kf];
      const uint32_t* pl = (const uint32_t*)&sAl_[wave * 16 + l15][kf];
      union { uint32_t u[4]; bf16x8 v; } ua, ul;
      ua.u[0] = ph[0]; ua.u[1] = ph[1]; ua.u[2] = ph[2]; ua.u[3] = ph[3];
      ul.u[0] = pl[0]; ul.u[1] = pl[1]; ul.u[2] = pl[2]; ul.u[3] = pl[3];
      ah = ua.v; al = ul.v;
    }
    #pragma unroll
    for (int f = 0; f < 4; f++) {
      const uint32_t* ph = (const uint32_t*)&sBh_[f * 16 + l15][kf];
      const uint32_t* pl = (const uint32_t*)&sBl_[f * 16 + l15][kf];
      union { uint32_t u[4]; bf16x8 v; } ub, ulb;
      ub.u[0]  = ph[0]; ub.u[1]  = ph[1]; ub.u[2]  = ph[2]; ub.u[3]  = ph[3];
      ulb.u[0] = pl[0]; ulb.u[1] = pl[1]; ulb.u[2] = pl[2]; ulb.u[3] = pl[3];
      acc[f] = __builtin_amdgcn_mfma_f32_16x16x32_bf16(ah, ub.v, acc[f], 0, 0, 0);
      acc[f] = __builtin_amdgcn_mfma_f32_16x16x32_bf16(al, ub.v, acc[f], 0, 0, 0);
      acc[f] = __builtin_amdgcn_mfma_f32_16x16x32_bf16(ah, ulb.v, acc[f], 0, 0, 0);
    }
    __syncthreads();
  }

  #pragma unroll
  for (int f = 0; f < 4; f++) {
    int col = n0 + f * 16 + l15;
    if (col >= N) continue;
    float bv = bs ? bs[col] : 0.f;
    #pragma unroll
    for (int i = 0; i < 4; i++) {
      int row = m0 + wave * 16 + (lane >> 4) * 4 + i;
      if (row >= M) continue;
      float v = acc[f][i] + bv;
      if (act == 1) v = gelu_tanh_f(v);
      if (R) v += R[(long long)row * ldc + col];
      C[(long long)row * ldc + col] = v;
    }
  }
}

// ---------------- small kernels ----------------
__global__ void k_embed(const int* __restrict__ ids, const float* __restrict__ wte,
                        const float* __restrict__ wpe, float* __restrict__ X) {
  int t = blockIdx.x; int s = t & (SEQ - 1);
  long long wb = (long long)ids[t] * DD;
  #pragma unroll
  for (int i = 0; i < 3; i++) {
    int d = threadIdx.x + 256 * i;
    X[(long long)t * DD + d] = wte[wb + d] + wpe[(long long)s * DD + d];
  }
}

__global__ void k_layernorm(const float* __restrict__ in, const float* __restrict__ g,
                            const float* __restrict__ b, float* __restrict__ out) {
  int t = blockIdx.x; int lane = threadIdx.x;
  float xv[12]; float s = 0.f, ss = 0.f;
  #pragma unroll
  for (int i = 0; i < 12; i++) {
    xv[i] = in[(long long)t * DD + lane + 64 * i];
    s += xv[i]; ss += xv[i] * xv[i];
  }
  for (int o = 32; o; o >>= 1) { s += __shfl_xor(s, o); ss += __shfl_xor(ss, o); }
  float mean = s * (1.f / DD);
  float var  = ss * (1.f / DD) - mean * mean;
  float rst  = rsqrtf(var + 1e-5f);
  #pragma unroll
  for (int i = 0; i < 12; i++) {
    int d = lane + 64 * i;
    out[(long long)t * DD + d] = (xv[i] - mean) * rst * g[d] + b[d];
  }
}

__global__ void k_rmsnorm(const float* __restrict__ in, const float* __restrict__ g,
                          float* __restrict__ out) {
  int t = blockIdx.x; int lane = threadIdx.x;
  float xv[12]; float ss = 0.f;
  #pragma unroll
  for (int i = 0; i < 12; i++) {
    xv[i] = in[(long long)t * DD + lane + 64 * i];
    ss += xv[i] * xv[i];
  }
  for (int o = 32; o; o >>= 1) ss += __shfl_xor(ss, o);
  float scale = 27.712812921102035f / fmaxf(sqrtf(ss), 1e-12f); // sqrt(768)/||x||
  #pragma unroll
  for (int i = 0; i < 12; i++) {
    int d = lane + 64 * i;
    out[(long long)t * DD + d] = xv[i] * scale * g[d];
  }
}

__global__ void k_softmax(float* __restrict__ S) { // grid 24*512, block 64
  int r = blockIdx.x; int q = r & (SEQ - 1);
  float* p = S + (long long)r * SEQ;
  int lane = threadIdx.x;
  float v[8]; float mx = -3.4e38f;
  #pragma unroll
  for (int i = 0; i < 8; i++) {
    int j = lane + 64 * i;
    v[i] = p[j] * 0.125f;
    if (j <= q) mx = fmaxf(mx, v[i]);
  }
  for (int o = 32; o; o >>= 1) mx = fmaxf(mx, __shfl_xor(mx, o));
  float s = 0.f;
  #pragma unroll
  for (int i = 0; i < 8; i++) {
    int j = lane + 64 * i;
    float e = (j <= q) ? expf(v[i] - mx) : 0.f;
    v[i] = e; s += e;
  }
  for (int o = 32; o; o >>= 1) s += __shfl_xor(s, o);
  float inv = 1.f / s;
  #pragma unroll
  for (int i = 0; i < 8; i++) p[lane + 64 * i] = v[i] * inv;
}

__global__ void k_geglu(const float* __restrict__ in, const float* __restrict__ mb,
                        float* __restrict__ out, int rows_per_mb) {
  int row = blockIdx.x;
  const float* mbp = mb + (long long)(row / rows_per_mb) * 2048;
  #pragma unroll
  for (int i = 0; i < 8; i++) {
    int j = threadIdx.x + 256 * i;
    float a = in[(long long)row * 4096 + j];
    float g = in[(long long)row * 4096 + 2048 + j];
    out[(long long)row * 2048 + j] = a * gelu_erf_f(g) * mbp[j];
  }
}

__global__ void k_zero(float* __restrict__ p, int n) {
  int i = blockIdx.x * blockDim.x + threadIdx.x;
  if (i < n) p[i] = 0.f;
}

__global__ void k_add(float* __restrict__ X, const float* __restrict__ Y, int n) {
  int i = blockIdx.x * 256 + threadIdx.x;
  if (i < n) X[i] += Y[i];
}

// gating: logits, softmax, top2, normalized gates, threefry route
__global__ void k_gate(const float* __restrict__ RB, const float* __restrict__ GW,
                       unsigned int fk0, unsigned int fk1,
                       int* __restrict__ e0a, int* __restrict__ e1a,
                       float* __restrict__ g0a, float* __restrict__ g1a,
                       int* __restrict__ r1a,
                       float* __restrict__ sum_raw, float* __restrict__ cnt1,
                       float* __restrict__ lse2) {
  int t = blockIdx.x; int lane = threadIdx.x;
  float acc[8] = {0, 0, 0, 0, 0, 0, 0, 0};
  for (int i = 0; i < 12; i++) {
    int d = lane + 64 * i;
    float xv = RB[(long long)t * DD + d];
    const float* w = GW + (long long)d * 8;
    #pragma unroll
    for (int e = 0; e < 8; e++) acc[e] += xv * w[e];
  }
  for (int o = 32; o; o >>= 1)
    #pragma unroll
    for (int e = 0; e < 8; e++) acc[e] += __shfl_xor(acc[e], o);
  if (lane == 0) {
    float m = acc[0];
    #pragma unroll
    for (int e = 1; e < 8; e++) m = fmaxf(m, acc[e]);
    float ex[8], s = 0.f;
    #pragma unroll
    for (int e = 0; e < 8; e++) { ex[e] = expf(acc[e] - m); s += ex[e]; }
    float raw[8];
    #pragma unroll
    for (int e = 0; e < 8; e++) raw[e] = ex[e] / s;
    float lse = m + logf(s);
    int b = t >> 9;
    #pragma unroll
    for (int e = 0; e < 8; e++) atomicAdd(&sum_raw[b * 8 + e], raw[e]);
    int e0 = 0;
    for (int e = 1; e < 8; e++) if (raw[e] > raw[e0]) e0 = e;
    int e1 = (e0 == 0) ? 1 : 0;
    for (int e = 0; e < 8; e++) if (e != e0 && raw[e] > raw[e1]) e1 = e;
    float gv0 = raw[e0], gv1 = raw[e1];
    float den = fmaxf(gv0 + gv1, 1e-9f);
    float g0 = gv0 / den, g1 = gv1 / den;
    uint32_t x0 = (uint32_t)t, x1 = (uint32_t)t + 1024u;
    threefry(fk0, fk1, x0, x1);
    union { uint32_t u; float f; } uf; uf.u = (x1 >> 9) | 0x3f800000u;
    float u = uf.f - 1.f;
    int r1 = (u < g1 * 5.f) ? 1 : 0;   // probs < gates/0.2
    e0a[t] = e0; e1a[t] = e1; g0a[t] = g0; g1a[t] = g1; r1a[t] = r1;
    atomicAdd(&cnt1[b * 8 + e0], 1.f);
    atomicAdd(lse2, lse * lse);
  }
}

// capacity scan: serial per (b,e); exact ST-MoE cumsum semantics
__global__ void k_scan(const int* __restrict__ e0a, const int* __restrict__ e1a,
                       const int* __restrict__ r1a,
                       int* __restrict__ s0a, int* __restrict__ s1a,
                       int* __restrict__ ts) {
  int tid = threadIdx.x;
  if (tid >= 16) return;
  int b = tid >> 3, e = tid & 7;
  int base = (e * 2 + b) * CAP;
  for (int c = 0; c < CAP; c++) ts[base + c] = -1;
  int c0 = 0;
  for (int n = 0; n < SEQ; n++) {
    int t = b * SEQ + n;
    if (e0a[t] == e) {
      if (c0 < CAP) { s0a[t] = c0; ts[base + c0] = t; } else s0a[t] = -1;
      c0++;
    }
  }
  int prev = c0 < CAP ? c0 : CAP;
  int c1 = 0;
  for (int n = 0; n < SEQ; n++) {
    int t = b * SEQ + n;
    if (e1a[t] == e) {
      if (r1a[t]) {
        int pos = prev + c1;
        if (pos < CAP) { s1a[t] = pos; ts[base + pos] = t; } else s1a[t] = -1;
        c1++;
      } else s1a[t] = -1;
    }
  }
}

__global__ void k_dispatch(const float* __restrict__ RB, const int* __restrict__ ts,
                           float* __restrict__ EIN) {
  int s = blockIdx.x;          // e*160 + b*80 + c == ts index
  int t = ts[s];
  #pragma unroll
  for (int i = 0; i < 3; i++) {
    int d = threadIdx.x + 256 * i;
    EIN[(long long)s * DD + d] = (t >= 0) ? RB[(long long)t * DD + d] : 0.f;
  }
}

__global__ void k_combine(const int* __restrict__ e0a, const int* __restrict__ e1a,
                          const int* __restrict__ s0a, const int* __restrict__ s1a,
                          const float* __restrict__ g0a, const float* __restrict__ g1a,
                          const float* __restrict__ EOUT, float* __restrict__ XM) {
  int t = blockIdx.x; int b = t >> 9;
  int s0 = s0a[t], s1 = s1a[t];
  long long r0 = ((long long)e0a[t] * 160 + b * CAP + s0) * DD;
  long long r1 = ((long long)e1a[t] * 160 + b * CAP + s1) * DD;
  float g0 = g0a[t], g1 = g1a[t];
  #pragma unroll
  for (int i = 0; i < 3; i++) {
    int d = threadIdx.x + 256 * i;
    float mo = 0.f;
    if (s0 >= 0) mo += g0 * EOUT[r0 + d];
    if (s1 >= 0) mo += g1 * EOUT[r1 + d];
    XM[(long long)t * DD + d] += mo;
  }
}

__global__ void k_aux(const float* __restrict__ sum_raw, const float* __restrict__ cnt1,
                      const float* __restrict__ lse2, float* __restrict__ aux) {
  if (threadIdx.x == 0 && blockIdx.x == 0) {
    float bal = 0.f;
    for (int i = 0; i < 16; i++) bal += sum_raw[i] * cnt1[i];
    bal *= 4.f / (512.f * 512.f);        // mean over (b,e) of means * E^2
    float zl = lse2[0] * (1.f / 1024.f);
    aux[0] += 0.01f * bal + 0.001f * zl;
  }
}

// ---------------- host ----------------
extern "C" void kernel_launch(void* const* d_in, const int* in_sizes, int n_in,
                              void* d_out, int out_size, void* d_ws, size_t ws_size,
                              hipStream_t stream) {
  const int*   ids  = (const int*)d_in[0];
  const float* wte  = (const float*)d_in[2];
  const float* wpe  = (const float*)d_in[3];
  const float* ln1g = (const float*)d_in[4];
  const float* ln1b = (const float*)d_in[5];
  const float* ln2g = (const float*)d_in[6];
  const float* ln2b = (const float*)d_in[7];
  const float* aqw  = (const float*)d_in[8];
  const float* aqb  = (const float*)d_in[9];
  const float* apw  = (const float*)d_in[10];
  const float* apb  = (const float*)d_in[11];
  const float* mfw  = (const float*)d_in[12];
  const float* mfb  = (const float*)d_in[13];
  const float* mpw  = (const float*)d_in[14];
  const float* mpb  = (const float*)d_in[15];
  const float* lnfg = (const float*)d_in[16];
  const float* lnfb = (const float*)d_in[17];
  const float* ffbng = (const float*)d_in[18];
  const float* ffbw1 = (const float*)d_in[19];
  const float* ffbb1 = (const float*)d_in[20];
  const float* ffbmb = (const float*)d_in[21];
  const float* ffbw2 = (const float*)d_in[22];
  const float* ffbb2 = (const float*)d_in[23];
  const float* ffang = (const float*)d_in[24];
  const float* ffaw1 = (const float*)d_in[25];
  const float* ffab1 = (const float*)d_in[26];
  const float* ffamb = (const float*)d_in[27];
  const float* ffaw2 = (const float*)d_in[28];
  const float* ffab2 = (const float*)d_in[29];
  const float* moeng = (const float*)d_in[30];
  const float* gw    = (const float*)d_in[31];
  const float* ew1   = (const float*)d_in[32];
  const float* eb1   = (const float*)d_in[33];
  const float* emb   = (const float*)d_in[34];
  const float* ew2   = (const float*)d_in[35];
  const float* eb2   = (const float*)d_in[36];

  float* ws = (float*)d_ws;
  float* X    = ws + 0;          // 786432
  float* LN   = ws + 786432;     // 786432
  float* RB   = ws + 1572864;    // 786432
  float* XM   = ws + 2359296;    // 786432
  float* QKV  = ws + 3145728;    // 2359296
  float* BIG  = ws + 5505024;    // 6291456 (scores / mlp-h / expert-h1)
  float* GB   = ws + 11796480;   // 2621440 (attno / geglu-out)
  float* EIN  = ws + 14417920;   // 983040
  float* EOUT = ws + 15400960;   // 983040
  float* MISC = ws + 16384000;
  int*   e0a = (int*)MISC;
  int*   e1a = e0a + 1024;
  int*   s0a = e1a + 1024;
  int*   s1a = s0a + 1024;
  int*   r1a = s1a + 1024;
  float* g0a = (float*)(r1a + 1024);
  float* g1a = g0a + 1024;
  int*   tsa = (int*)(g1a + 1024);      // 1280
  float* sum_raw = (float*)(tsa + 1280); // 16
  float* cnt1 = sum_raw + 16;            // 16
  float* lse2 = cnt1 + 16;               // 1

  float* logits = (float*)d_out;
  float* aux = logits + AUXOFF;

  // folded threefry keys for layers 0 and 3 (fold_in(key(1234), i))
  unsigned int fk[2][2];
  { uint32_t a = 0, b = 0; threefry(0u, 1234u, a, b); fk[0][0] = a; fk[0][1] = b; }
  { uint32_t a = 0, b = 3; threefry(0u, 1234u, a, b); fk[1][0] = a; fk[1][1] = b; }

  auto gemm = [&](bool transB, const float* A, const float* Bm, float* Cm,
                  const float* bias, const float* resid,
                  int M, int N, int K, int lda, int ldb, int ldc,
                  int batches, int nh,
                  long long sAb, long long sAh, long long sBb, long long sBh,
                  long long sCb, long long sCh, long long sBias, int act) {
    dim3 g((N + 63) / 64, (M + 63) / 64, batches);
    if (transB)
      k_gemm<true><<<g, 256, 0, stream>>>(A, Bm, Cm, bias, resid, M, N, K, lda, ldb, ldc,
                                          nh, sAb, sAh, sBb, sBh, sCb, sCh, sBias, act);
    else
      k_gemm<false><<<g, 256, 0, stream>>>(A, Bm, Cm, bias, resid, M, N, K, lda, ldb, ldc,
                                           nh, sAb, sAh, sBb, sBh, sCb, sCh, sBias, act);
  };

  auto moe = [&](unsigned int fk0, unsigned int fk1) {
    // st_ff(ffb): XM = geglu-ff(rms(LN)) + LN
    k_rmsnorm<<<1024, 64, 0, stream>>>(LN, ffbng, RB);
    gemm(false, RB, ffbw1, BIG, ffbb1, nullptr, 1024, 4096, 768, 768, 4096, 4096,
         1, 1, 0, 0, 0, 0, 0, 0, 0, 0);
    k_geglu<<<1024, 256, 0, stream>>>(BIG, ffbmb, GB, 1024);
    gemm(false, GB, ffbw2, XM, ffbb2, LN, 1024, 768, 2048, 2048, 768, 768,
         1, 1, 0, 0, 0, 0, 0, 0, 0, 0);
    // gating on rms(XM)
    k_rmsnorm<<<1024, 64, 0, stream>>>(XM, moeng, RB);
    k_zero<<<1, 64, 0, stream>>>(sum_raw, 33);
    k_gate<<<1024, 64, 0, stream>>>(RB, gw, fk0, fk1, e0a, e1a, g0a, g1a, r1a,
                                    sum_raw, cnt1, lse2);
    k_scan<<<1, 64, 0, stream>>>(e0a, e1a, r1a, s0a, s1a, tsa);
    k_dispatch<<<1280, 256, 0, stream>>>(RB, tsa, EIN);
    // experts
    gemm(false, EIN, ew1, BIG, eb1, nullptr, 160, 4096, 768, 768, 4096, 4096,
         8, 1, 122880, 0, 3145728, 0, 655360, 0, 4096, 0);
    k_geglu<<<1280, 256, 0, stream>>>(BIG, emb, GB, 160);
    gemm(false, GB, ew2, EOUT, eb2, nullptr, 160, 768, 2048, 2048, 768, 768,
         8, 1, 327680, 0, 1572864, 0, 122880, 0, 768, 0);
    k_combine<<<1024, 256, 0, stream>>>(e0a, e1a, s0a, s1a, g0a, g1a, EOUT, XM);
    k_aux<<<1, 1, 0, stream>>>(sum_raw, cnt1, lse2, aux);
    // st_ff(ffa): XM = geglu-ff(rms(XM)) + XM
    k_rmsnorm<<<1024, 64, 0, stream>>>(XM, ffang, RB);
    gemm(false, RB, ffaw1, BIG, ffab1, nullptr, 1024, 4096, 768, 768, 4096, 4096,
         1, 1, 0, 0, 0, 0, 0, 0, 0, 0);
    k_geglu<<<1024, 256, 0, stream>>>(BIG, ffamb, GB, 1024);
    gemm(false, GB, ffaw2, XM, ffab2, XM, 1024, 768, 2048, 2048, 768, 768,
         1, 1, 0, 0, 0, 0, 0, 0, 0, 0);
    k_add<<<3072, 256, 0, stream>>>(X, XM, 786432);
  };

  k_zero<<<1, 64, 0, stream>>>(aux, 1);
  k_embed<<<1024, 256, 0, stream>>>(ids, wte, wpe, X);

  for (int i = 0; i < 6; i++) {
    // attention
    k_layernorm<<<1024, 64, 0, stream>>>(X, ln1g + i * 768, ln1b + i * 768, LN);
    gemm(false, LN, aqw + (long long)i * 768 * 2304, QKV, aqb + (long long)i * 2304,
         nullptr, 1024, 2304, 768, 768, 2304, 2304, 1, 1, 0, 0, 0, 0, 0, 0, 0, 0);
    // scores = Q @ K^T (batched over b,h)
    gemm(true, QKV, QKV + 768, BIG, nullptr, nullptr, 512, 512, 64, 2304, 2304, 512,
         24, 12, 1179648, 64, 1179648, 64, 3145728, 262144, 0, 0);
    k_softmax<<<12288, 64, 0, stream>>>(BIG);
    // O = P @ V
    gemm(false, BIG, QKV + 1536, GB, nullptr, nullptr, 512, 64, 512, 512, 2304, 768,
         24, 12, 3145728, 262144, 1179648, 64, 393216, 64, 0, 0);
    // X += O @ Wo + bo
    gemm(false, GB, apw + (long long)i * 768 * 768, X, apb + (long long)i * 768, X,
         1024, 768, 768, 768, 768, 768, 1, 1, 0, 0, 0, 0, 0, 0, 0, 0);
    // FF
    k_layernorm<<<1024, 64, 0, stream>>>(X, ln2g + i * 768, ln2b + i * 768, LN);
    if (i == 0 || i == 3) {
      moe(fk[i == 0 ? 0 : 1][0], fk[i == 0 ? 0 : 1][1]);
    } else {
      gemm(false, LN, mfw + (long long)i * 768 * 3072, BIG, mfb + (long long)i * 3072,
           nullptr, 1024, 3072, 768, 768, 3072, 3072, 1, 1, 0, 0, 0, 0, 0, 0, 0, 1);
      gemm(false, BIG, mpw + (long long)i * 3072 * 768, X, mpb + (long long)i * 768, X,
           1024, 768, 3072, 3072, 768, 768, 1, 1, 0, 0, 0, 0, 0, 0, 0, 0);
    }
  }

  k_layernorm<<<1024, 64, 0, stream>>>(X, lnfg, lnfb, LN);
  // logits = LN @ wte^T
  gemm(true, LN, wte, logits, nullptr, nullptr, 1024, VOCAB, 768, 768, 768, VOCAB,
       1, 1, 0, 0, 0, 0, 0, 0, 0, 0);
}

// Round 4
// 4411.872 us; speedup vs baseline: 1.7709x; 1.7709x over previous
//
#include <hip/hip_runtime.h>
#include <cstdint>

// ---------------- dims ----------------
#define DD     768
#define NTOK   1024
#define SEQ    512
#define NHEAD  12
#define HDIM   64
#define VOCAB  50258
#define CAP    80
#define AUXOFF 51464192LL   // 2*512*50258

typedef short bf16x8 __attribute__((ext_vector_type(8)));
typedef float f32x4  __attribute__((ext_vector_type(4)));

// ---------------- threefry2x32 (exact JAX) ----------------
__host__ __device__ inline void threefry(uint32_t k0, uint32_t k1,
                                         uint32_t& x0, uint32_t& x1) {
  uint32_t ks0 = k0, ks1 = k1, ks2 = k0 ^ k1 ^ 0x1BD11BDAu;
  x0 += ks0; x1 += ks1;
#define RND(r) { x0 += x1; x1 = (x1 << (r)) | (x1 >> (32 - (r))); x1 ^= x0; }
  RND(13) RND(15) RND(26) RND(6)   x0 += ks1; x1 += ks2 + 1u;
  RND(17) RND(29) RND(16) RND(24)  x0 += ks2; x1 += ks0 + 2u;
  RND(13) RND(15) RND(26) RND(6)   x0 += ks0; x1 += ks1 + 3u;
  RND(17) RND(29) RND(16) RND(24)  x0 += ks1; x1 += ks2 + 4u;
  RND(13) RND(15) RND(26) RND(6)   x0 += ks2; x1 += ks0 + 5u;
#undef RND
}

__device__ inline unsigned short f2bf(float f) {
  union { float f; uint32_t u; } v; v.f = f;
  uint32_t u = v.u;
  return (unsigned short)((u + 0x7FFFu + ((u >> 16) & 1u)) >> 16);
}
__device__ inline float bf2f(unsigned short h) {
  union { uint32_t u; float f; } v; v.u = ((uint32_t)h) << 16; return v.f;
}
__device__ inline float gelu_tanh_f(float x) {
  float x3 = x * x * x;
  return 0.5f * x * (1.f + tanhf(0.7978845608028654f * (x + 0.044715f * x3)));
}
__device__ inline float gelu_erf_f(float x) {
  return 0.5f * x * (1.f + erff(x * 0.7071067811865476f));
}

// ---------------- old GEMM (bf16x3 split in-kernel) — fallback + attention ----
template<bool TRANS_B>
__global__ __launch_bounds__(256)
void k_gemm(const float* __restrict__ Ag, const float* __restrict__ Bg,
            float* __restrict__ Cg, const float* __restrict__ biasg,
            const float* __restrict__ residg,
            int M, int N, int K, int lda, int ldb, int ldc, int nh,
            long long sAb, long long sAh, long long sBb, long long sBh,
            long long sCb, long long sCh, long long sBias, int act)
{
  const int z  = blockIdx.z;
  const int zb = z / nh, zh = z - zb * nh;
  const float* A = Ag + zb * sAb + zh * sAh;
  const float* B = Bg + zb * sBb + zh * sBh;
  float*       C = Cg + zb * sCb + zh * sCh;
  const float* R = residg ? residg + zb * sCb + zh * sCh : nullptr;
  const float* bs = biasg ? biasg + (long long)z * sBias : nullptr;

  const int m0 = blockIdx.y * 64;
  const int n0 = blockIdx.x * 64;

  __shared__ __attribute__((aligned(16))) unsigned short sAh_[64][36];
  __shared__ __attribute__((aligned(16))) unsigned short sAl_[64][36];
  __shared__ __attribute__((aligned(16))) unsigned short sBh_[64][36];
  __shared__ __attribute__((aligned(16))) unsigned short sBl_[64][36];

  const int tid  = threadIdx.x;
  const int wave = tid >> 6;
  const int lane = tid & 63;
  const int l15  = lane & 15;
  const int kf   = (lane >> 4) * 8;

  f32x4 zf = {0.f, 0.f, 0.f, 0.f};
  f32x4 acc[4] = {zf, zf, zf, zf};

  const int ar = tid >> 2;
  const int ac = (tid & 3) * 8;

  for (int kk = 0; kk < K; kk += 32) {
    {
      float v[8];
      if (m0 + ar < M) {
        const float* p = A + (long long)(m0 + ar) * lda + kk + ac;
        #pragma unroll
        for (int j = 0; j < 8; j++) v[j] = p[j];
      } else {
        #pragma unroll
        for (int j = 0; j < 8; j++) v[j] = 0.f;
      }
      #pragma unroll
      for (int j = 0; j < 8; j += 2) {
        unsigned short h0 = f2bf(v[j]), h1 = f2bf(v[j + 1]);
        float r0 = v[j] - bf2f(h0), r1 = v[j + 1] - bf2f(h1);
        *(uint32_t*)&sAh_[ar][ac + j] = (uint32_t)h0 | ((uint32_t)h1 << 16);
        *(uint32_t*)&sAl_[ar][ac + j] = (uint32_t)f2bf(r0) | ((uint32_t)f2bf(r1) << 16);
      }
    }
    if (TRANS_B) {
      float v[8];
      int nrow = n0 + ar;
      if (nrow < N) {
        const float* p = B + (long long)nrow * ldb + kk + ac;
        #pragma unroll
        for (int j = 0; j < 8; j++) v[j] = p[j];
      } else {
        #pragma unroll
        for (int j = 0; j < 8; j++) v[j] = 0.f;
      }
      #pragma unroll
      for (int j = 0; j < 8; j += 2) {
        unsigned short h0 = f2bf(v[j]), h1 = f2bf(v[j + 1]);
        float r0 = v[j] - bf2f(h0), r1 = v[j + 1] - bf2f(h1);
        *(uint32_t*)&sBh_[ar][ac + j] = (uint32_t)h0 | ((uint32_t)h1 << 16);
        *(uint32_t*)&sBl_[ar][ac + j] = (uint32_t)f2bf(r0) | ((uint32_t)f2bf(r1) << 16);
      }
    } else {
      int n = n0 + lane;
      bool ok = n < N;
      #pragma unroll
      for (int i = 0; i < 8; i++) {
        int k = (tid >> 6) + i * 4;
        float v = ok ? B[(long long)(kk + k) * ldb + n] : 0.f;
        unsigned short h = f2bf(v);
        sBh_[lane][k] = h;
        sBl_[lane][k] = f2bf(v - bf2f(h));
      }
    }
    __syncthreads();

    bf16x8 a, al;
    {
      const uint32_t* ph = (const uint32_t*)&sAh_[wave * 16 + l15][kf];
      const uint32_t* pl = (const uint32_t*)&sAl_[wave * 16 + l15][kf];
      union { uint32_t u[4]; bf16x8 v; } ua, ul;
      ua.u[0] = ph[0]; ua.u[1] = ph[1]; ua.u[2] = ph[2]; ua.u[3] = ph[3];
      ul.u[0] = pl[0]; ul.u[1] = pl[1]; ul.u[2] = pl[2]; ul.u[3] = pl[3];
      a = ua.v; al = ul.v;
    }
    #pragma unroll
    for (int f = 0; f < 4; f++) {
      const uint32_t* ph = (const uint32_t*)&sBh_[f * 16 + l15][kf];
      const uint32_t* pl = (const uint32_t*)&sBl_[f * 16 + l15][kf];
      union { uint32_t u[4]; bf16x8 v; } ub, ulb;
      ub.u[0]  = ph[0]; ub.u[1]  = ph[1]; ub.u[2]  = ph[2]; ub.u[3]  = ph[3];
      ulb.u[0] = pl[0]; ulb.u[1] = pl[1]; ulb.u[2] = pl[2]; ulb.u[3] = pl[3];
      acc[f] = __builtin_amdgcn_mfma_f32_16x16x32_bf16(a,  ub.v,  acc[f], 0, 0, 0);
      acc[f] = __builtin_amdgcn_mfma_f32_16x16x32_bf16(al, ub.v,  acc[f], 0, 0, 0);
      acc[f] = __builtin_amdgcn_mfma_f32_16x16x32_bf16(a,  ulb.v, acc[f], 0, 0, 0);
    }
    __syncthreads();
  }

  #pragma unroll
  for (int f = 0; f < 4; f++) {
    int col = n0 + f * 16 + l15;
    if (col >= N) continue;
    float bv = bs ? bs[col] : 0.f;
    #pragma unroll
    for (int i = 0; i < 4; i++) {
      int row = m0 + wave * 16 + (lane >> 4) * 4 + i;
      if (row >= M) continue;
      float v = acc[f][i] + bv;
      if (act == 1) v = gelu_tanh_f(v);
      if (R) v += R[(long long)row * ldc + col];
      C[(long long)row * ldc + col] = v;
    }
  }
}

// ---------------- weight-split GEMM: B pre-split [N][K] bf16 hi/lo ----------
// tile 64(M) x 128(N), BK=32, 4 waves (2x2), 24 MFMA / K-step
__global__ __launch_bounds__(256)
void k_gemmw(const float* __restrict__ Ag, const unsigned short* __restrict__ Bhg,
             const unsigned short* __restrict__ Blg, float* __restrict__ Cg,
             const float* __restrict__ biasg, const float* __restrict__ residg,
             int M, int N, int K, int ldc,
             long long sAz, long long sBz, long long sCz, long long sBias,
             int act, int swz)
{
  const int z = blockIdx.z;
  const float* A = Ag + z * sAz;
  const unsigned short* BH = Bhg + z * sBz;
  const unsigned short* BL = Blg + z * sBz;
  float* C = Cg + z * sCz;
  const float* R = residg ? residg + z * sCz : nullptr;
  const float* bs = biasg ? biasg + z * sBias : nullptr;

  int xt, yt;
  if (swz) {
    int gx = gridDim.x, gy = gridDim.y;
    int bid = blockIdx.y * gx + blockIdx.x;
    int nblk = gx * gy;
    int q = nblk >> 3, r = nblk & 7;
    int xcd = bid & 7, idx = bid >> 3;
    int nl = (xcd < r ? xcd * (q + 1) : r * (q + 1) + (xcd - r) * q) + idx;
    yt = nl % gy; xt = nl / gy;     // m fast -> B-panel reuse within XCD L2
  } else { xt = blockIdx.x; yt = blockIdx.y; }

  const int m0 = yt * 64, n0 = xt * 128;

  // stride 40 shorts = 80 B: 16B-aligned for b128; 20 dwords -> 2-way max on frag reads
  __shared__ __attribute__((aligned(16))) unsigned short sAh[64][40];
  __shared__ __attribute__((aligned(16))) unsigned short sAl[64][40];
  __shared__ __attribute__((aligned(16))) unsigned short sBh[128][40];
  __shared__ __attribute__((aligned(16))) unsigned short sBl[128][40];

  const int tid = threadIdx.x, wave = tid >> 6, lane = tid & 63;
  const int l15 = lane & 15, kf = (lane >> 4) * 8;
  const int wr = (wave >> 1) * 32, wc = (wave & 1) * 64;

  f32x4 zf = {0.f, 0.f, 0.f, 0.f};
  f32x4 acc[2][4] = {{zf, zf, zf, zf}, {zf, zf, zf, zf}};

  const int ar = tid >> 2, ac = (tid & 3) * 8;
  const int br = tid >> 1, bc = (tid & 1) * 16;

  for (int kk = 0; kk < K; kk += 32) {
    { // A stage (f32 -> hi/lo split)
      float v[8];
      if (m0 + ar < M) {
        const float* p = A + (long long)(m0 + ar) * K + kk + ac;
        #pragma unroll
        for (int j = 0; j < 8; j++) v[j] = p[j];
      } else {
        #pragma unroll
        for (int j = 0; j < 8; j++) v[j] = 0.f;
      }
      #pragma unroll
      for (int j = 0; j < 8; j += 4) {
        unsigned short h0 = f2bf(v[j]),     h1 = f2bf(v[j + 1]);
        unsigned short h2 = f2bf(v[j + 2]), h3 = f2bf(v[j + 3]);
        uint2 ph, pl;
        ph.x = (uint32_t)h0 | ((uint32_t)h1 << 16);
        ph.y = (uint32_t)h2 | ((uint32_t)h3 << 16);
        pl.x = (uint32_t)f2bf(v[j] - bf2f(h0))     | ((uint32_t)f2bf(v[j + 1] - bf2f(h1)) << 16);
        pl.y = (uint32_t)f2bf(v[j + 2] - bf2f(h2)) | ((uint32_t)f2bf(v[j + 3] - bf2f(h3)) << 16);
        *(uint2*)&sAh[ar][ac + j] = ph;
        *(uint2*)&sAl[ar][ac + j] = pl;
      }
    }
    { // B stage: pure copy of pre-split planes
      int nrow = n0 + br;
      if (nrow < N) {
        const uint4* ph = (const uint4*)(BH + (long long)nrow * K + kk + bc);
        const uint4* pl = (const uint4*)(BL + (long long)nrow * K + kk + bc);
        *(uint4*)&sBh[br][bc]     = ph[0];
        *(uint4*)&sBh[br][bc + 8] = ph[1];
        *(uint4*)&sBl[br][bc]     = pl[0];
        *(uint4*)&sBl[br][bc + 8] = pl[1];
      } else {
        uint4 z4 = {0, 0, 0, 0};
        *(uint4*)&sBh[br][bc] = z4; *(uint4*)&sBh[br][bc + 8] = z4;
        *(uint4*)&sBl[br][bc] = z4; *(uint4*)&sBl[br][bc + 8] = z4;
      }
    }
    __syncthreads();

    bf16x8 ah[2], al[2];
    #pragma unroll
    for (int i = 0; i < 2; i++) {
      union { uint4 q; bf16x8 v; } ua, ul;
      ua.q = *(const uint4*)&sAh[wr + i * 16 + l15][kf];
      ul.q = *(const uint4*)&sAl[wr + i * 16 + l15][kf];
      ah[i] = ua.v; al[i] = ul.v;
    }
    #pragma unroll
    for (int j = 0; j < 4; j++) {
      union { uint4 q; bf16x8 v; } ub, ulb;
      ub.q  = *(const uint4*)&sBh[wc + j * 16 + l15][kf];
      ulb.q = *(const uint4*)&sBl[wc + j * 16 + l15][kf];
      #pragma unroll
      for (int i = 0; i < 2; i++) {
        acc[i][j] = __builtin_amdgcn_mfma_f32_16x16x32_bf16(ah[i], ub.v,  acc[i][j], 0, 0, 0);
        acc[i][j] = __builtin_amdgcn_mfma_f32_16x16x32_bf16(al[i], ub.v,  acc[i][j], 0, 0, 0);
        acc[i][j] = __builtin_amdgcn_mfma_f32_16x16x32_bf16(ah[i], ulb.v, acc[i][j], 0, 0, 0);
      }
    }
    __syncthreads();
  }

  #pragma unroll
  for (int j = 0; j < 4; j++) {
    int col = n0 + wc + j * 16 + l15;
    if (col >= N) continue;
    float bv = bs ? bs[col] : 0.f;
    #pragma unroll
    for (int i = 0; i < 2; i++) {
      #pragma unroll
      for (int rr = 0; rr < 4; rr++) {
        int row = m0 + wr + i * 16 + (lane >> 4) * 4 + rr;
        if (row >= M) continue;
        float v = acc[i][j][rr] + bv;
        if (act == 1) v = gelu_tanh_f(v);
        if (R) v += R[(long long)row * ldc + col];
        C[(long long)row * ldc + col] = v;
      }
    }
  }
}

// ---------------- weight pre-split kernels ----------------
// split only: src [N][K] f32 -> hi/lo planes (same layout)
__global__ void k_split(const float* __restrict__ src, unsigned short* __restrict__ dh,
                        unsigned short* __restrict__ dl, long long n) {
  long long i = ((long long)blockIdx.x * 256 + threadIdx.x) * 4;
  if (i >= n) return;
  float4 v = *(const float4*)(src + i);
  float vv[4] = {v.x, v.y, v.z, v.w};
  unsigned short h[4], l[4];
  #pragma unroll
  for (int j = 0; j < 4; j++) {
    h[j] = f2bf(vv[j]);
    l[j] = f2bf(vv[j] - bf2f(h[j]));
  }
  *(ushort4*)(dh + i) = make_ushort4(h[0], h[1], h[2], h[3]);
  *(ushort4*)(dl + i) = make_ushort4(l[0], l[1], l[2], l[3]);
}

// split + transpose: src [K][N] f32 -> dst [N][K] hi/lo
__global__ void k_split_t(const float* __restrict__ src, unsigned short* __restrict__ dh,
                          unsigned short* __restrict__ dl, int K, int N,
                          long long sSrc, long long sDst) {
  __shared__ float t[32][33];
  const float* S = src + (long long)blockIdx.z * sSrc;
  unsigned short* DH = dh + (long long)blockIdx.z * sDst;
  unsigned short* DL = dl + (long long)blockIdx.z * sDst;
  int n0 = blockIdx.x * 32, k0 = blockIdx.y * 32;
  int tx = threadIdx.x & 31, ty = threadIdx.x >> 5;  // ty 0..7
  #pragma unroll
  for (int i = 0; i < 32; i += 8)
    t[ty + i][tx] = S[(long long)(k0 + ty + i) * N + n0 + tx];
  __syncthreads();
  #pragma unroll
  for (int i = 0; i < 32; i += 8) {
    float v = t[tx][ty + i];
    unsigned short h = f2bf(v);
    long long o = (long long)(n0 + ty + i) * K + k0 + tx;
    DH[o] = h;
    DL[o] = f2bf(v - bf2f(h));
  }
}

// ---------------- small kernels ----------------
__global__ void k_embed(const int* __restrict__ ids, const float* __restrict__ wte,
                        const float* __restrict__ wpe, float* __restrict__ X) {
  int t = blockIdx.x; int s = t & (SEQ - 1);
  long long wb = (long long)ids[t] * DD;
  #pragma unroll
  for (int i = 0; i < 3; i++) {
    int d = threadIdx.x + 256 * i;
    X[(long long)t * DD + d] = wte[wb + d] + wpe[(long long)s * DD + d];
  }
}

__global__ void k_layernorm(const float* __restrict__ in, const float* __restrict__ g,
                            const float* __restrict__ b, float* __restrict__ out) {
  int t = blockIdx.x; int lane = threadIdx.x;
  float xv[12]; float s = 0.f, ss = 0.f;
  #pragma unroll
  for (int i = 0; i < 12; i++) {
    xv[i] = in[(long long)t * DD + lane + 64 * i];
    s += xv[i]; ss += xv[i] * xv[i];
  }
  for (int o = 32; o; o >>= 1) { s += __shfl_xor(s, o); ss += __shfl_xor(ss, o); }
  float mean = s * (1.f / DD);
  float var  = ss * (1.f / DD) - mean * mean;
  float rst  = rsqrtf(var + 1e-5f);
  #pragma unroll
  for (int i = 0; i < 12; i++) {
    int d = lane + 64 * i;
    out[(long long)t * DD + d] = (xv[i] - mean) * rst * g[d] + b[d];
  }
}

__global__ void k_rmsnorm(const float* __restrict__ in, const float* __restrict__ g,
                          float* __restrict__ out) {
  int t = blockIdx.x; int lane = threadIdx.x;
  float xv[12]; float ss = 0.f;
  #pragma unroll
  for (int i = 0; i < 12; i++) {
    xv[i] = in[(long long)t * DD + lane + 64 * i];
    ss += xv[i] * xv[i];
  }
  for (int o = 32; o; o >>= 1) ss += __shfl_xor(ss, o);
  float scale = 27.712812921102035f / fmaxf(sqrtf(ss), 1e-12f);
  #pragma unroll
  for (int i = 0; i < 12; i++) {
    int d = lane + 64 * i;
    out[(long long)t * DD + d] = xv[i] * scale * g[d];
  }
}

__global__ void k_softmax(float* __restrict__ S) {
  int r = blockIdx.x; int q = r & (SEQ - 1);
  float* p = S + (long long)r * SEQ;
  int lane = threadIdx.x;
  float v[8]; float mx = -3.4e38f;
  #pragma unroll
  for (int i = 0; i < 8; i++) {
    int j = lane + 64 * i;
    v[i] = p[j] * 0.125f;
    if (j <= q) mx = fmaxf(mx, v[i]);
  }
  for (int o = 32; o; o >>= 1) mx = fmaxf(mx, __shfl_xor(mx, o));
  float s = 0.f;
  #pragma unroll
  for (int i = 0; i < 8; i++) {
    int j = lane + 64 * i;
    float e = (j <= q) ? expf(v[i] - mx) : 0.f;
    v[i] = e; s += e;
  }
  for (int o = 32; o; o >>= 1) s += __shfl_xor(s, o);
  float inv = 1.f / s;
  #pragma unroll
  for (int i = 0; i < 8; i++) p[lane + 64 * i] = v[i] * inv;
}

__global__ void k_geglu(const float* __restrict__ in, const float* __restrict__ mb,
                        float* __restrict__ out, int rows_per_mb) {
  int row = blockIdx.x;
  const float* mbp = mb + (long long)(row / rows_per_mb) * 2048;
  #pragma unroll
  for (int i = 0; i < 8; i++) {
    int j = threadIdx.x + 256 * i;
    float a = in[(long long)row * 4096 + j];
    float g = in[(long long)row * 4096 + 2048 + j];
    out[(long long)row * 2048 + j] = a * gelu_erf_f(g) * mbp[j];
  }
}

__global__ void k_zero(float* __restrict__ p, int n) {
  int i = blockIdx.x * blockDim.x + threadIdx.x;
  if (i < n) p[i] = 0.f;
}

__global__ void k_add(float* __restrict__ X, const float* __restrict__ Y, int n) {
  int i = blockIdx.x * 256 + threadIdx.x;
  if (i < n) X[i] += Y[i];
}

__global__ void k_gate(const float* __restrict__ RB, const float* __restrict__ GW,
                       unsigned int fk0, unsigned int fk1,
                       int* __restrict__ e0a, int* __restrict__ e1a,
                       float* __restrict__ g0a, float* __restrict__ g1a,
                       int* __restrict__ r1a,
                       float* __restrict__ sum_raw, float* __restrict__ cnt1,
                       float* __restrict__ lse2) {
  int t = blockIdx.x; int lane = threadIdx.x;
  float acc[8] = {0, 0, 0, 0, 0, 0, 0, 0};
  for (int i = 0; i < 12; i++) {
    int d = lane + 64 * i;
    float xv = RB[(long long)t * DD + d];
    const float* w = GW + (long long)d * 8;
    #pragma unroll
    for (int e = 0; e < 8; e++) acc[e] += xv * w[e];
  }
  for (int o = 32; o; o >>= 1)
    #pragma unroll
    for (int e = 0; e < 8; e++) acc[e] += __shfl_xor(acc[e], o);
  if (lane == 0) {
    float m = acc[0];
    #pragma unroll
    for (int e = 1; e < 8; e++) m = fmaxf(m, acc[e]);
    float ex[8], s = 0.f;
    #pragma unroll
    for (int e = 0; e < 8; e++) { ex[e] = expf(acc[e] - m); s += ex[e]; }
    float raw[8];
    #pragma unroll
    for (int e = 0; e < 8; e++) raw[e] = ex[e] / s;
    float lse = m + logf(s);
    int b = t >> 9;
    #pragma unroll
    for (int e = 0; e < 8; e++) atomicAdd(&sum_raw[b * 8 + e], raw[e]);
    int e0 = 0;
    for (int e = 1; e < 8; e++) if (raw[e] > raw[e0]) e0 = e;
    int e1 = (e0 == 0) ? 1 : 0;
    for (int e = 0; e < 8; e++) if (e != e0 && raw[e] > raw[e1]) e1 = e;
    float gv0 = raw[e0], gv1 = raw[e1];
    float den = fmaxf(gv0 + gv1, 1e-9f);
    float g0 = gv0 / den, g1 = gv1 / den;
    uint32_t x0 = (uint32_t)t, x1 = (uint32_t)t + 1024u;
    threefry(fk0, fk1, x0, x1);
    union { uint32_t u; float f; } uf; uf.u = (x1 >> 9) | 0x3f800000u;
    float u = uf.f - 1.f;
    int r1 = (u < g1 * 5.f) ? 1 : 0;
    e0a[t] = e0; e1a[t] = e1; g0a[t] = g0; g1a[t] = g1; r1a[t] = r1;
    atomicAdd(&cnt1[b * 8 + e0], 1.f);
    atomicAdd(lse2, lse * lse);
  }
}

__global__ void k_scan(const int* __restrict__ e0a, const int* __restrict__ e1a,
                       const int* __restrict__ r1a,
                       int* __restrict__ s0a, int* __restrict__ s1a,
                       int* __restrict__ ts) {
  int tid = threadIdx.x;
  if (tid >= 16) return;
  int b = tid >> 3, e = tid & 7;
  int base = (e * 2 + b) * CAP;
  for (int c = 0; c < CAP; c++) ts[base + c] = -1;
  int c0 = 0;
  for (int n = 0; n < SEQ; n++) {
    int t = b * SEQ + n;
    if (e0a[t] == e) {
      if (c0 < CAP) { s0a[t] = c0; ts[base + c0] = t; } else s0a[t] = -1;
      c0++;
    }
  }
  int prev = c0 < CAP ? c0 : CAP;
  int c1 = 0;
  for (int n = 0; n < SEQ; n++) {
    int t = b * SEQ + n;
    if (e1a[t] == e) {
      if (r1a[t]) {
        int pos = prev + c1;
        if (pos < CAP) { s1a[t] = pos; ts[base + pos] = t; } else s1a[t] = -1;
        c1++;
      } else s1a[t] = -1;
    }
  }
}

__global__ void k_dispatch(const float* __restrict__ RB, const int* __restrict__ ts,
                           float* __restrict__ EIN) {
  int s = blockIdx.x;
  int t = ts[s];
  #pragma unroll
  for (int i = 0; i < 3; i++) {
    int d = threadIdx.x + 256 * i;
    EIN[(long long)s * DD + d] = (t >= 0) ? RB[(long long)t * DD + d] : 0.f;
  }
}

__global__ void k_combine(const int* __restrict__ e0a, const int* __restrict__ e1a,
                          const int* __restrict__ s0a, const int* __restrict__ s1a,
                          const float* __restrict__ g0a, const float* __restrict__ g1a,
                          const float* __restrict__ EOUT, float* __restrict__ XM) {
  int t = blockIdx.x; int b = t >> 9;
  int s0 = s0a[t], s1 = s1a[t];
  long long r0 = ((long long)e0a[t] * 160 + b * CAP + s0) * DD;
  long long r1 = ((long long)e1a[t] * 160 + b * CAP + s1) * DD;
  float g0 = g0a[t], g1 = g1a[t];
  #pragma unroll
  for (int i = 0; i < 3; i++) {
    int d = threadIdx.x + 256 * i;
    float mo = 0.f;
    if (s0 >= 0) mo += g0 * EOUT[r0 + d];
    if (s1 >= 0) mo += g1 * EOUT[r1 + d];
    XM[(long long)t * DD + d] += mo;
  }
}

__global__ void k_aux(const float* __restrict__ sum_raw, const float* __restrict__ cnt1,
                      const float* __restrict__ lse2, float* __restrict__ aux) {
  if (threadIdx.x == 0 && blockIdx.x == 0) {
    float bal = 0.f;
    for (int i = 0; i < 16; i++) bal += sum_raw[i] * cnt1[i];
    bal *= 4.f / (512.f * 512.f);
    float zl = lse2[0] * (1.f / 1024.f);
    aux[0] += 0.01f * bal + 0.001f * zl;
  }
}

// ---------------- host ----------------
extern "C" void kernel_launch(void* const* d_in, const int* in_sizes, int n_in,
                              void* d_out, int out_size, void* d_ws, size_t ws_size,
                              hipStream_t stream) {
  const int*   ids  = (const int*)d_in[0];
  const float* wte  = (const float*)d_in[2];
  const float* wpe  = (const float*)d_in[3];
  const float* ln1g = (const float*)d_in[4];
  const float* ln1b = (const float*)d_in[5];
  const float* ln2g = (const float*)d_in[6];
  const float* ln2b = (const float*)d_in[7];
  const float* aqw  = (const float*)d_in[8];
  const float* aqb  = (const float*)d_in[9];
  const float* apw  = (const float*)d_in[10];
  const float* apb  = (const float*)d_in[11];
  const float* mfw  = (const float*)d_in[12];
  const float* mfb  = (const float*)d_in[13];
  const float* mpw  = (const float*)d_in[14];
  const float* mpb  = (const float*)d_in[15];
  const float* lnfg = (const float*)d_in[16];
  const float* lnfb = (const float*)d_in[17];
  const float* ffbng = (const float*)d_in[18];
  const float* ffbw1 = (const float*)d_in[19];
  const float* ffbb1 = (const float*)d_in[20];
  const float* ffbmb = (const float*)d_in[21];
  const float* ffbw2 = (const float*)d_in[22];
  const float* ffbb2 = (const float*)d_in[23];
  const float* ffang = (const float*)d_in[24];
  const float* ffaw1 = (const float*)d_in[25];
  const float* ffab1 = (const float*)d_in[26];
  const float* ffamb = (const float*)d_in[27];
  const float* ffaw2 = (const float*)d_in[28];
  const float* ffab2 = (const float*)d_in[29];
  const float* moeng = (const float*)d_in[30];
  const float* gw    = (const float*)d_in[31];
  const float* ew1   = (const float*)d_in[32];
  const float* eb1   = (const float*)d_in[33];
  const float* emb   = (const float*)d_in[34];
  const float* ew2   = (const float*)d_in[35];
  const float* eb2   = (const float*)d_in[36];

  float* ws = (float*)d_ws;
  float* X    = ws + 0;
  float* LN   = ws + 786432;
  float* RB   = ws + 1572864;
  float* XM   = ws + 2359296;
  float* QKV  = ws + 3145728;
  float* BIG  = ws + 5505024;
  float* GB   = ws + 11796480;
  float* EIN  = ws + 14417920;
  float* EOUT = ws + 15400960;
  float* MISC = ws + 16384000;
  int*   e0a = (int*)MISC;
  int*   e1a = e0a + 1024;
  int*   s0a = e1a + 1024;
  int*   s1a = s0a + 1024;
  int*   r1a = s1a + 1024;
  float* g0a = (float*)(r1a + 1024);
  float* g1a = g0a + 1024;
  int*   tsa = (int*)(g1a + 1024);
  float* sum_raw = (float*)(tsa + 1280);
  float* cnt1 = sum_raw + 16;
  float* lse2 = cnt1 + 16;

  float* logits = (float*)d_out;
  float* aux = logits + AUXOFF;

  // ---- pre-split weight region (shorts), after f32 region ----
  const long long E_wte = 38598144LL, E_qkv = 1769472LL, E_apr = 589824LL;
  const long long E_fc = 2359296LL, E_mpr = 2359296LL;
  const long long E_fb1 = 3145728LL, E_fb2 = 1572864LL;
  const long long E_ew1 = 3145728LL, E_ew2 = 1572864LL;
  const long long o_wte = 0;
  const long long o_qkv = o_wte + 2 * E_wte;          // 77,196,288
  const long long o_apr = o_qkv + 12 * E_qkv;         // 98,429,952
  const long long o_fc  = o_apr + 12 * E_apr;         // 105,507,840
  const long long o_mpr = o_fc  + 8 * E_fc;           // 124,382,208
  const long long o_fb1 = o_mpr + 8 * E_mpr;          // 143,256,576
  const long long o_fb2 = o_fb1 + 2 * E_fb1;
  const long long o_fa1 = o_fb2 + 2 * E_fb2;
  const long long o_fa2 = o_fa1 + 2 * E_fb1;
  const long long o_ew1 = o_fa2 + 2 * E_fb2;
  const long long o_ew2 = o_ew1 + 16 * E_ew1;
  const long long o_end = o_ew2 + 16 * E_ew2;         // 237,628,416 shorts
  unsigned short* SP = (unsigned short*)(ws + 16400000);
  const bool useSplit = ((long long)ws_size >= 16400000LL * 4 + o_end * 2);

  unsigned int fk[2][2];
  { uint32_t a = 0, b = 0; threefry(0u, 1234u, a, b); fk[0][0] = a; fk[0][1] = b; }
  { uint32_t a = 0, b = 3; threefry(0u, 1234u, a, b); fk[1][0] = a; fk[1][1] = b; }

  auto gemm = [&](bool transB, const float* A, const float* Bm, float* Cm,
                  const float* bias, const float* resid,
                  int M, int N, int K, int lda, int ldb, int ldc,
                  int batches, int nh,
                  long long sAb, long long sAh, long long sBb, long long sBh,
                  long long sCb, long long sCh, long long sBias, int act) {
    dim3 g((N + 63) / 64, (M + 63) / 64, batches);
    if (transB)
      k_gemm<true><<<g, 256, 0, stream>>>(A, Bm, Cm, bias, resid, M, N, K, lda, ldb, ldc,
                                          nh, sAb, sAh, sBb, sBh, sCb, sCh, sBias, act);
    else
      k_gemm<false><<<g, 256, 0, stream>>>(A, Bm, Cm, bias, resid, M, N, K, lda, ldb, ldc,
                                           nh, sAb, sAh, sBb, sBh, sCb, sCh, sBias, act);
  };

  // weight GEMM: split path (B pre-split [N][K]) or fallback (f32 B [K][N])
  auto wgemm = [&](const float* A, const float* Bf, long long bOff, long long bE,
                   float* Cm, const float* bias, const float* resid,
                   int M, int N, int K, int ldc, int nz,
                   long long sAz, long long sBf, long long sCz, long long sBias,
                   int act, int swz) {
    if (useSplit) {
      dim3 g((N + 127) / 128, (M + 63) / 64, nz);
      k_gemmw<<<g, 256, 0, stream>>>(A, SP + bOff, SP + bOff + bE, Cm, bias, resid,
                                     M, N, K, ldc, sAz, 2 * bE, sCz, sBias, act, swz);
    } else {
      gemm(false, A, Bf, Cm, bias, resid, M, N, K, K, N, ldc,
           nz, 1, sAz, 0, sBf, 0, sCz, 0, sBias, act);
    }
  };

  if (useSplit) {
    auto splitT = [&](const float* src, long long dOff, long long E, int K_, int N_,
                      int nz, long long sSrc) {
      k_split_t<<<dim3(N_ / 32, K_ / 32, nz), 256, 0, stream>>>(
          src, SP + dOff, SP + dOff + E, K_, N_, sSrc, 2 * E);
    };
    k_split<<<(int)((E_wte / 4 + 255) / 256), 256, 0, stream>>>(
        wte, SP + o_wte, SP + o_wte + E_wte, E_wte);
    splitT(aqw, o_qkv, E_qkv, 768, 2304, 6, 768LL * 2304);
    splitT(apw, o_apr, E_apr, 768, 768, 6, 768LL * 768);
    int mlpLayers[4] = {1, 2, 4, 5};
    for (int s = 0; s < 4; s++) {
      int L = mlpLayers[s];
      splitT(mfw + (long long)L * E_fc,  o_fc  + s * 2 * E_fc,  E_fc,  768, 3072, 1, 0);
      splitT(mpw + (long long)L * E_mpr, o_mpr + s * 2 * E_mpr, E_mpr, 3072, 768, 1, 0);
    }
    splitT(ffbw1, o_fb1, E_fb1, 768, 4096, 1, 0);
    splitT(ffbw2, o_fb2, E_fb2, 2048, 768, 1, 0);
    splitT(ffaw1, o_fa1, E_fb1, 768, 4096, 1, 0);
    splitT(ffaw2, o_fa2, E_fb2, 2048, 768, 1, 0);
    splitT(ew1, o_ew1, E_ew1, 768, 4096, 8, (long long)768 * 4096);
    splitT(ew2, o_ew2, E_ew2, 2048, 768, 8, (long long)2048 * 768);
  }

  auto moe = [&](unsigned int fk0, unsigned int fk1) {
    k_rmsnorm<<<1024, 64, 0, stream>>>(LN, ffbng, RB);
    wgemm(RB, ffbw1, o_fb1, E_fb1, BIG, ffbb1, nullptr,
          1024, 4096, 768, 4096, 1, 0, 0, 0, 0, 0, 1);
    k_geglu<<<1024, 256, 0, stream>>>(BIG, ffbmb, GB, 1024);
    wgemm(GB, ffbw2, o_fb2, E_fb2, XM, ffbb2, LN,
          1024, 768, 2048, 768, 1, 0, 0, 0, 0, 0, 1);
    k_rmsnorm<<<1024, 64, 0, stream>>>(XM, moeng, RB);
    k_zero<<<1, 64, 0, stream>>>(sum_raw, 33);
    k_gate<<<1024, 64, 0, stream>>>(RB, gw, fk0, fk1, e0a, e1a, g0a, g1a, r1a,
                                    sum_raw, cnt1, lse2);
    k_scan<<<1, 64, 0, stream>>>(e0a, e1a, r1a, s0a, s1a, tsa);
    k_dispatch<<<1280, 256, 0, stream>>>(RB, tsa, EIN);
    wgemm(EIN, ew1, o_ew1, E_ew1, BIG, eb1, nullptr,
          160, 4096, 768, 4096, 8, 122880, 3145728, 655360, 4096, 0, 0);
    k_geglu<<<1280, 256, 0, stream>>>(BIG, emb, GB, 160);
    wgemm(GB, ew2, o_ew2, E_ew2, EOUT, eb2, nullptr,
          160, 768, 2048, 768, 8, 327680, 1572864, 122880, 768, 0, 0);
    k_combine<<<1024, 256, 0, stream>>>(e0a, e1a, s0a, s1a, g0a, g1a, EOUT, XM);
    k_aux<<<1, 1, 0, stream>>>(sum_raw, cnt1, lse2, aux);
    k_rmsnorm<<<1024, 64, 0, stream>>>(XM, ffang, RB);
    wgemm(RB, ffaw1, o_fa1, E_fb1, BIG, ffab1, nullptr,
          1024, 4096, 768, 4096, 1, 0, 0, 0, 0, 0, 1);
    k_geglu<<<1024, 256, 0, stream>>>(BIG, ffamb, GB, 1024);
    wgemm(GB, ffaw2, o_fa2, E_fb2, XM, ffab2, XM,
          1024, 768, 2048, 768, 1, 0, 0, 0, 0, 0, 1);
    k_add<<<3072, 256, 0, stream>>>(X, XM, 786432);
  };

  k_zero<<<1, 64, 0, stream>>>(aux, 1);
  k_embed<<<1024, 256, 0, stream>>>(ids, wte, wpe, X);

  for (int i = 0; i < 6; i++) {
    k_layernorm<<<1024, 64, 0, stream>>>(X, ln1g + i * 768, ln1b + i * 768, LN);
    wgemm(LN, aqw + (long long)i * 768 * 2304, o_qkv + (long long)i * 2 * E_qkv, E_qkv,
          QKV, aqb + (long long)i * 2304, nullptr,
          1024, 2304, 768, 2304, 1, 0, 0, 0, 0, 0, 1);
    gemm(true, QKV, QKV + 768, BIG, nullptr, nullptr, 512, 512, 64, 2304, 2304, 512,
         24, 12, 1179648, 64, 1179648, 64, 3145728, 262144, 0, 0);
    k_softmax<<<12288, 64, 0, stream>>>(BIG);
    gemm(false, BIG, QKV + 1536, GB, nullptr, nullptr, 512, 64, 512, 512, 2304, 768,
         24, 12, 3145728, 262144, 1179648, 64, 393216, 64, 0, 0);
    wgemm(GB, apw + (long long)i * 768 * 768, o_apr + (long long)i * 2 * E_apr, E_apr,
          X, apb + (long long)i * 768, X,
          1024, 768, 768, 768, 1, 0, 0, 0, 0, 0, 1);
    k_layernorm<<<1024, 64, 0, stream>>>(X, ln2g + i * 768, ln2b + i * 768, LN);
    if (i == 0 || i == 3) {
      moe(fk[i == 0 ? 0 : 1][0], fk[i == 0 ? 0 : 1][1]);
    } else {
      int slot = (i < 3) ? (i - 1) : (i - 2);
      wgemm(LN, mfw + (long long)i * 768 * 3072, o_fc + (long long)slot * 2 * E_fc, E_fc,
            BIG, mfb + (long long)i * 3072, nullptr,
            1024, 3072, 768, 3072, 1, 0, 0, 0, 0, 1, 1);
      wgemm(BIG, mpw + (long long)i * 3072 * 768, o_mpr + (long long)slot * 2 * E_mpr, E_mpr,
            X, mpb + (long long)i * 768, X,
            1024, 768, 3072, 768, 1, 0, 0, 0, 0, 0, 1);
    }
  }

  k_layernorm<<<1024, 64, 0, stream>>>(X, lnfg, lnfb, LN);
  if (useSplit) {
    wgemm(LN, nullptr, o_wte, E_wte, logits, nullptr, nullptr,
          1024, VOCAB, 768, VOCAB, 1, 0, 0, 0, 0, 0, 1);
  } else {
    gemm(true, LN, wte, logits, nullptr, nullptr, 1024, VOCAB, 768, 768, 768, VOCAB,
         1, 1, 0, 0, 0, 0, 0, 0, 0, 0);
  }
}

// Round 6
// 4133.623 us; speedup vs baseline: 1.8901x; 1.0673x over previous
//
#include <hip/hip_runtime.h>
#include <cstdint>

// ---------------- dims ----------------
#define DD     768
#define NTOK   1024
#define SEQ    512
#define NHEAD  12
#define HDIM   64
#define VOCAB  50258
#define CAP    80
#define AUXOFF 51464192LL   // 2*512*50258

typedef short bf16x8 __attribute__((ext_vector_type(8)));
typedef float f32x4  __attribute__((ext_vector_type(4)));

// ---------------- threefry2x32 (exact JAX) ----------------
__host__ __device__ inline void threefry(uint32_t k0, uint32_t k1,
                                         uint32_t& x0, uint32_t& x1) {
  uint32_t ks0 = k0, ks1 = k1, ks2 = k0 ^ k1 ^ 0x1BD11BDAu;
  x0 += ks0; x1 += ks1;
#define RND(r) { x0 += x1; x1 = (x1 << (r)) | (x1 >> (32 - (r))); x1 ^= x0; }
  RND(13) RND(15) RND(26) RND(6)   x0 += ks1; x1 += ks2 + 1u;
  RND(17) RND(29) RND(16) RND(24)  x0 += ks2; x1 += ks0 + 2u;
  RND(13) RND(15) RND(26) RND(6)   x0 += ks0; x1 += ks1 + 3u;
  RND(17) RND(29) RND(16) RND(24)  x0 += ks1; x1 += ks2 + 4u;
  RND(13) RND(15) RND(26) RND(6)   x0 += ks2; x1 += ks0 + 5u;
#undef RND
}

__device__ inline unsigned short f2bf(float f) {
  union { float f; uint32_t u; } v; v.f = f;
  uint32_t u = v.u;
  return (unsigned short)((u + 0x7FFFu + ((u >> 16) & 1u)) >> 16);
}
__device__ inline float bf2f(unsigned short h) {
  union { uint32_t u; float f; } v; v.u = ((uint32_t)h) << 16; return v.f;
}
__device__ inline float gelu_tanh_f(float x) {
  float x3 = x * x * x;
  return 0.5f * x * (1.f + tanhf(0.7978845608028654f * (x + 0.044715f * x3)));
}
__device__ inline float gelu_erf_f(float x) {
  return 0.5f * x * (1.f + erff(x * 0.7071067811865476f));
}

// ---------------- old GEMM (in-kernel split) — attention + fallback ----------
// optional split output (osplit=1): write C hi/lo planes instead of f32
template<bool TRANS_B>
__global__ __launch_bounds__(256)
void k_gemm(const float* __restrict__ Ag, const float* __restrict__ Bg,
            float* __restrict__ Cg, unsigned short* __restrict__ Chg,
            unsigned short* __restrict__ Clg,
            const float* __restrict__ biasg, const float* __restrict__ residg,
            int M, int N, int K, int lda, int ldb, int ldc, int nh,
            long long sAb, long long sAh, long long sBb, long long sBh,
            long long sCb, long long sCh, long long sBias, int act, int osplit)
{
  const int z  = blockIdx.z;
  const int zb = z / nh, zh = z - zb * nh;
  const float* A = Ag + zb * sAb + zh * sAh;
  const float* B = Bg + zb * sBb + zh * sBh;
  const long long cOff = zb * sCb + zh * sCh;
  const float* R = residg ? residg + cOff : nullptr;
  const float* bs = biasg ? biasg + (long long)z * sBias : nullptr;

  const int m0 = blockIdx.y * 64;
  const int n0 = blockIdx.x * 64;

  __shared__ __attribute__((aligned(16))) unsigned short sAh_[64][36];
  __shared__ __attribute__((aligned(16))) unsigned short sAl_[64][36];
  __shared__ __attribute__((aligned(16))) unsigned short sBh_[64][36];
  __shared__ __attribute__((aligned(16))) unsigned short sBl_[64][36];

  const int tid  = threadIdx.x;
  const int wave = tid >> 6;
  const int lane = tid & 63;
  const int l15  = lane & 15;
  const int kf   = (lane >> 4) * 8;

  f32x4 zf = {0.f, 0.f, 0.f, 0.f};
  f32x4 acc[4] = {zf, zf, zf, zf};

  const int ar = tid >> 2;
  const int ac = (tid & 3) * 8;

  for (int kk = 0; kk < K; kk += 32) {
    {
      float v[8];
      if (m0 + ar < M) {
        const float* p = A + (long long)(m0 + ar) * lda + kk + ac;
        #pragma unroll
        for (int j = 0; j < 8; j++) v[j] = p[j];
      } else {
        #pragma unroll
        for (int j = 0; j < 8; j++) v[j] = 0.f;
      }
      #pragma unroll
      for (int j = 0; j < 8; j += 2) {
        unsigned short h0 = f2bf(v[j]), h1 = f2bf(v[j + 1]);
        float r0 = v[j] - bf2f(h0), r1 = v[j + 1] - bf2f(h1);
        *(uint32_t*)&sAh_[ar][ac + j] = (uint32_t)h0 | ((uint32_t)h1 << 16);
        *(uint32_t*)&sAl_[ar][ac + j] = (uint32_t)f2bf(r0) | ((uint32_t)f2bf(r1) << 16);
      }
    }
    if (TRANS_B) {
      float v[8];
      int nrow = n0 + ar;
      if (nrow < N) {
        const float* p = B + (long long)nrow * ldb + kk + ac;
        #pragma unroll
        for (int j = 0; j < 8; j++) v[j] = p[j];
      } else {
        #pragma unroll
        for (int j = 0; j < 8; j++) v[j] = 0.f;
      }
      #pragma unroll
      for (int j = 0; j < 8; j += 2) {
        unsigned short h0 = f2bf(v[j]), h1 = f2bf(v[j + 1]);
        float r0 = v[j] - bf2f(h0), r1 = v[j + 1] - bf2f(h1);
        *(uint32_t*)&sBh_[ar][ac + j] = (uint32_t)h0 | ((uint32_t)h1 << 16);
        *(uint32_t*)&sBl_[ar][ac + j] = (uint32_t)f2bf(r0) | ((uint32_t)f2bf(r1) << 16);
      }
    } else {
      int n = n0 + lane;
      bool ok = n < N;
      #pragma unroll
      for (int i = 0; i < 8; i++) {
        int k = (tid >> 6) + i * 4;
        float v = ok ? B[(long long)(kk + k) * ldb + n] : 0.f;
        unsigned short h = f2bf(v);
        sBh_[lane][k] = h;
        sBl_[lane][k] = f2bf(v - bf2f(h));
      }
    }
    __syncthreads();

    bf16x8 a, al;
    {
      const uint32_t* ph = (const uint32_t*)&sAh_[wave * 16 + l15][kf];
      const uint32_t* pl = (const uint32_t*)&sAl_[wave * 16 + l15][kf];
      union { uint32_t u[4]; bf16x8 v; } ua, ul;
      ua.u[0] = ph[0]; ua.u[1] = ph[1]; ua.u[2] = ph[2]; ua.u[3] = ph[3];
      ul.u[0] = pl[0]; ul.u[1] = pl[1]; ul.u[2] = pl[2]; ul.u[3] = pl[3];
      a = ua.v; al = ul.v;
    }
    #pragma unroll
    for (int f = 0; f < 4; f++) {
      const uint32_t* ph = (const uint32_t*)&sBh_[f * 16 + l15][kf];
      const uint32_t* pl = (const uint32_t*)&sBl_[f * 16 + l15][kf];
      union { uint32_t u[4]; bf16x8 v; } ub, ulb;
      ub.u[0]  = ph[0]; ub.u[1]  = ph[1]; ub.u[2]  = ph[2]; ub.u[3]  = ph[3];
      ulb.u[0] = pl[0]; ulb.u[1] = pl[1]; ulb.u[2] = pl[2]; ulb.u[3] = pl[3];
      acc[f] = __builtin_amdgcn_mfma_f32_16x16x32_bf16(a,  ub.v,  acc[f], 0, 0, 0);
      acc[f] = __builtin_amdgcn_mfma_f32_16x16x32_bf16(al, ub.v,  acc[f], 0, 0, 0);
      acc[f] = __builtin_amdgcn_mfma_f32_16x16x32_bf16(a,  ulb.v, acc[f], 0, 0, 0);
    }
    __syncthreads();
  }

  #pragma unroll
  for (int f = 0; f < 4; f++) {
    int col = n0 + f * 16 + l15;
    if (col >= N) continue;
    float bv = bs ? bs[col] : 0.f;
    #pragma unroll
    for (int i = 0; i < 4; i++) {
      int row = m0 + wave * 16 + (lane >> 4) * 4 + i;
      if (row >= M) continue;
      float v = acc[f][i] + bv;
      if (act == 1) v = gelu_tanh_f(v);
      if (R) v += R[(long long)row * ldc + col];
      long long idx = cOff + (long long)row * ldc + col;
      if (osplit) {
        unsigned short h = f2bf(v);
        Chg[idx] = h;
        Clg[idx] = f2bf(v - bf2f(h));
      } else {
        Cg[idx] = v;
      }
    }
  }
}

// ---------------- weight-split GEMM: A and B pre-split bf16 hi/lo planes ----
// tile 64(M) x 128(N), BK=32, 4 waves (2x2), 24 MFMA / K-step
__global__ __launch_bounds__(256)
void k_gemmw(const unsigned short* __restrict__ Ahg, const unsigned short* __restrict__ Alg,
             const unsigned short* __restrict__ Bhg, const unsigned short* __restrict__ Blg,
             float* __restrict__ Cg, unsigned short* __restrict__ Chg,
             unsigned short* __restrict__ Clg,
             const float* __restrict__ biasg, const float* __restrict__ residg,
             int M, int N, int K, int ldc,
             long long sAz, long long sBz, long long sCz, long long sBias,
             int act, int swz)
{
  const int z = blockIdx.z;
  const unsigned short* AH = Ahg + z * sAz;
  const unsigned short* AL = Alg + z * sAz;
  const unsigned short* BH = Bhg + z * sBz;
  const unsigned short* BL = Blg + z * sBz;
  const float* R = residg ? residg + z * sCz : nullptr;
  const float* bs = biasg ? biasg + z * sBias : nullptr;

  int xt, yt;
  if (swz) {
    int gx = gridDim.x, gy = gridDim.y;
    int bid = blockIdx.y * gx + blockIdx.x;
    int nblk = gx * gy;
    int q = nblk >> 3, r = nblk & 7;
    int xcd = bid & 7, idx = bid >> 3;
    int nl = (xcd < r ? xcd * (q + 1) : r * (q + 1) + (xcd - r) * q) + idx;
    yt = nl % gy; xt = nl / gy;     // m fast -> B-panel reuse within XCD L2
  } else { xt = blockIdx.x; yt = blockIdx.y; }

  const int m0 = yt * 64, n0 = xt * 128;

  __shared__ __attribute__((aligned(16))) unsigned short sAh[64][40];
  __shared__ __attribute__((aligned(16))) unsigned short sAl[64][40];
  __shared__ __attribute__((aligned(16))) unsigned short sBh[128][40];
  __shared__ __attribute__((aligned(16))) unsigned short sBl[128][40];

  const int tid = threadIdx.x, wave = tid >> 6, lane = tid & 63;
  const int l15 = lane & 15, kf = (lane >> 4) * 8;
  const int wr = (wave >> 1) * 32, wc = (wave & 1) * 64;

  f32x4 zf = {0.f, 0.f, 0.f, 0.f};
  f32x4 acc[2][4] = {{zf, zf, zf, zf}, {zf, zf, zf, zf}};

  const int ar = tid >> 2, ac = (tid & 3) * 8;
  const int br = tid >> 1, bc = (tid & 1) * 16;

  for (int kk = 0; kk < K; kk += 32) {
    { // A stage: pure plane copy
      if (m0 + ar < M) {
        long long o = (long long)(m0 + ar) * K + kk + ac;
        *(uint4*)&sAh[ar][ac] = *(const uint4*)(AH + o);
        *(uint4*)&sAl[ar][ac] = *(const uint4*)(AL + o);
      } else {
        uint4 z4 = {0, 0, 0, 0};
        *(uint4*)&sAh[ar][ac] = z4;
        *(uint4*)&sAl[ar][ac] = z4;
      }
    }
    { // B stage: pure plane copy
      int nrow = n0 + br;
      if (nrow < N) {
        const uint4* ph = (const uint4*)(BH + (long long)nrow * K + kk + bc);
        const uint4* pl = (const uint4*)(BL + (long long)nrow * K + kk + bc);
        *(uint4*)&sBh[br][bc]     = ph[0];
        *(uint4*)&sBh[br][bc + 8] = ph[1];
        *(uint4*)&sBl[br][bc]     = pl[0];
        *(uint4*)&sBl[br][bc + 8] = pl[1];
      } else {
        uint4 z4 = {0, 0, 0, 0};
        *(uint4*)&sBh[br][bc] = z4; *(uint4*)&sBh[br][bc + 8] = z4;
        *(uint4*)&sBl[br][bc] = z4; *(uint4*)&sBl[br][bc + 8] = z4;
      }
    }
    __syncthreads();

    bf16x8 ah[2], al[2];
    #pragma unroll
    for (int i = 0; i < 2; i++) {
      union { uint4 q; bf16x8 v; } ua, ul;
      ua.q = *(const uint4*)&sAh[wr + i * 16 + l15][kf];
      ul.q = *(const uint4*)&sAl[wr + i * 16 + l15][kf];
      ah[i] = ua.v; al[i] = ul.v;
    }
    #pragma unroll
    for (int j = 0; j < 4; j++) {
      union { uint4 q; bf16x8 v; } ub, ulb;
      ub.q  = *(const uint4*)&sBh[wc + j * 16 + l15][kf];
      ulb.q = *(const uint4*)&sBl[wc + j * 16 + l15][kf];
      #pragma unroll
      for (int i = 0; i < 2; i++) {
        acc[i][j] = __builtin_amdgcn_mfma_f32_16x16x32_bf16(ah[i], ub.v,  acc[i][j], 0, 0, 0);
        acc[i][j] = __builtin_amdgcn_mfma_f32_16x16x32_bf16(al[i], ub.v,  acc[i][j], 0, 0, 0);
        acc[i][j] = __builtin_amdgcn_mfma_f32_16x16x32_bf16(ah[i], ulb.v, acc[i][j], 0, 0, 0);
      }
    }
    __syncthreads();
  }

  const int osplit = (Chg != nullptr);
  #pragma unroll
  for (int j = 0; j < 4; j++) {
    int col = n0 + wc + j * 16 + l15;
    if (col >= N) continue;
    float bv = bs ? bs[col] : 0.f;
    #pragma unroll
    for (int i = 0; i < 2; i++) {
      #pragma unroll
      for (int rr = 0; rr < 4; rr++) {
        int row = m0 + wr + i * 16 + (lane >> 4) * 4 + rr;
        if (row >= M) continue;
        float v = acc[i][j][rr] + bv;
        if (act == 1) v = gelu_tanh_f(v);
        if (R) v += R[(long long)row * ldc + col];
        long long idx = (long long)z * sCz + (long long)row * ldc + col;
        if (osplit) {
          unsigned short h = f2bf(v);
          Chg[idx] = h;
          Clg[idx] = f2bf(v - bf2f(h));
        } else {
          Cg[idx] = v;
        }
      }
    }
  }
}

// ---------------- weight pre-split kernels ----------------
__global__ void k_split(const float* __restrict__ src, unsigned short* __restrict__ dh,
                        unsigned short* __restrict__ dl, long long n) {
  long long i = ((long long)blockIdx.x * 256 + threadIdx.x) * 4;
  if (i >= n) return;
  float4 v = *(const float4*)(src + i);
  float vv[4] = {v.x, v.y, v.z, v.w};
  unsigned short h[4], l[4];
  #pragma unroll
  for (int j = 0; j < 4; j++) {
    h[j] = f2bf(vv[j]);
    l[j] = f2bf(vv[j] - bf2f(h[j]));
  }
  *(ushort4*)(dh + i) = make_ushort4(h[0], h[1], h[2], h[3]);
  *(ushort4*)(dl + i) = make_ushort4(l[0], l[1], l[2], l[3]);
}

__global__ void k_split_t(const float* __restrict__ src, unsigned short* __restrict__ dh,
                          unsigned short* __restrict__ dl, int K, int N,
                          long long sSrc, long long sDst) {
  __shared__ float t[32][33];
  const float* S = src + (long long)blockIdx.z * sSrc;
  unsigned short* DH = dh + (long long)blockIdx.z * sDst;
  unsigned short* DL = dl + (long long)blockIdx.z * sDst;
  int n0 = blockIdx.x * 32, k0 = blockIdx.y * 32;
  int tx = threadIdx.x & 31, ty = threadIdx.x >> 5;
  #pragma unroll
  for (int i = 0; i < 32; i += 8)
    t[ty + i][tx] = S[(long long)(k0 + ty + i) * N + n0 + tx];
  __syncthreads();
  #pragma unroll
  for (int i = 0; i < 32; i += 8) {
    float v = t[tx][ty + i];
    unsigned short h = f2bf(v);
    long long o = (long long)(n0 + ty + i) * K + k0 + tx;
    DH[o] = h;
    DL[o] = f2bf(v - bf2f(h));
  }
}

// ---------------- small kernels ----------------
__global__ void k_embed(const int* __restrict__ ids, const float* __restrict__ wte,
                        const float* __restrict__ wpe, float* __restrict__ X) {
  int t = blockIdx.x; int s = t & (SEQ - 1);
  long long wb = (long long)ids[t] * DD;
  #pragma unroll
  for (int i = 0; i < 3; i++) {
    int d = threadIdx.x + 256 * i;
    X[(long long)t * DD + d] = wte[wb + d] + wpe[(long long)s * DD + d];
  }
}

// layernorm; write f32 and/or split planes
__global__ void k_layernorm(const float* __restrict__ in, const float* __restrict__ g,
                            const float* __restrict__ b, float* __restrict__ out,
                            unsigned short* __restrict__ oh, unsigned short* __restrict__ ol) {
  int t = blockIdx.x; int lane = threadIdx.x;
  float xv[12]; float s = 0.f, ss = 0.f;
  #pragma unroll
  for (int i = 0; i < 12; i++) {
    xv[i] = in[(long long)t * DD + lane + 64 * i];
    s += xv[i]; ss += xv[i] * xv[i];
  }
  for (int o = 32; o; o >>= 1) { s += __shfl_xor(s, o); ss += __shfl_xor(ss, o); }
  float mean = s * (1.f / DD);
  float var  = ss * (1.f / DD) - mean * mean;
  float rst  = rsqrtf(var + 1e-5f);
  #pragma unroll
  for (int i = 0; i < 12; i++) {
    int d = lane + 64 * i;
    float y = (xv[i] - mean) * rst * g[d] + b[d];
    long long idx = (long long)t * DD + d;
    out[idx] = y;
    if (oh) {
      unsigned short h = f2bf(y);
      oh[idx] = h;
      ol[idx] = f2bf(y - bf2f(h));
    }
  }
}

__global__ void k_rmsnorm(const float* __restrict__ in, const float* __restrict__ g,
                          float* __restrict__ out,
                          unsigned short* __restrict__ oh, unsigned short* __restrict__ ol) {
  int t = blockIdx.x; int lane = threadIdx.x;
  float xv[12]; float ss = 0.f;
  #pragma unroll
  for (int i = 0; i < 12; i++) {
    xv[i] = in[(long long)t * DD + lane + 64 * i];
    ss += xv[i] * xv[i];
  }
  for (int o = 32; o; o >>= 1) ss += __shfl_xor(ss, o);
  float scale = 27.712812921102035f / fmaxf(sqrtf(ss), 1e-12f);
  #pragma unroll
  for (int i = 0; i < 12; i++) {
    int d = lane + 64 * i;
    float y = xv[i] * scale * g[d];
    long long idx = (long long)t * DD + d;
    out[idx] = y;
    if (oh) {
      unsigned short h = f2bf(y);
      oh[idx] = h;
      ol[idx] = f2bf(y - bf2f(h));
    }
  }
}

__global__ void k_softmax(float* __restrict__ S) {
  int r = blockIdx.x; int q = r & (SEQ - 1);
  float* p = S + (long long)r * SEQ;
  int lane = threadIdx.x;
  float v[8]; float mx = -3.4e38f;
  #pragma unroll
  for (int i = 0; i < 8; i++) {
    int j = lane + 64 * i;
    v[i] = p[j] * 0.125f;
    if (j <= q) mx = fmaxf(mx, v[i]);
  }
  for (int o = 32; o; o >>= 1) mx = fmaxf(mx, __shfl_xor(mx, o));
  float s = 0.f;
  #pragma unroll
  for (int i = 0; i < 8; i++) {
    int j = lane + 64 * i;
    float e = (j <= q) ? expf(v[i] - mx) : 0.f;
    v[i] = e; s += e;
  }
  for (int o = 32; o; o >>= 1) s += __shfl_xor(s, o);
  float inv = 1.f / s;
  #pragma unroll
  for (int i = 0; i < 8; i++) p[lane + 64 * i] = v[i] * inv;
}

// geglu; writes f32 (of==1) or split planes
__global__ void k_geglu(const float* __restrict__ in, const float* __restrict__ mb,
                        float* __restrict__ outf, unsigned short* __restrict__ oh,
                        unsigned short* __restrict__ ol, int rows_per_mb) {
  int row = blockIdx.x;
  const float* mbp = mb + (long long)(row / rows_per_mb) * 2048;
  #pragma unroll
  for (int i = 0; i < 8; i++) {
    int j = threadIdx.x + 256 * i;
    float a = in[(long long)row * 4096 + j];
    float g = in[(long long)row * 4096 + 2048 + j];
    float y = a * gelu_erf_f(g) * mbp[j];
    long long idx = (long long)row * 2048 + j;
    if (oh) {
      unsigned short h = f2bf(y);
      oh[idx] = h;
      ol[idx] = f2bf(y - bf2f(h));
    } else {
      outf[idx] = y;
    }
  }
}

__global__ void k_zero(float* __restrict__ p, int n) {
  int i = blockIdx.x * blockDim.x + threadIdx.x;
  if (i < n) p[i] = 0.f;
}

__global__ void k_add(float* __restrict__ X, const float* __restrict__ Y, int n) {
  int i = blockIdx.x * 256 + threadIdx.x;
  if (i < n) X[i] += Y[i];
}

__global__ void k_gate(const float* __restrict__ RB, const float* __restrict__ GW,
                       unsigned int fk0, unsigned int fk1,
                       int* __restrict__ e0a, int* __restrict__ e1a,
                       float* __restrict__ g0a, float* __restrict__ g1a,
                       int* __restrict__ r1a,
                       float* __restrict__ sum_raw, float* __restrict__ cnt1,
                       float* __restrict__ lse2) {
  int t = blockIdx.x; int lane = threadIdx.x;
  float acc[8] = {0, 0, 0, 0, 0, 0, 0, 0};
  for (int i = 0; i < 12; i++) {
    int d = lane + 64 * i;
    float xv = RB[(long long)t * DD + d];
    const float* w = GW + (long long)d * 8;
    #pragma unroll
    for (int e = 0; e < 8; e++) acc[e] += xv * w[e];
  }
  for (int o = 32; o; o >>= 1)
    #pragma unroll
    for (int e = 0; e < 8; e++) acc[e] += __shfl_xor(acc[e], o);
  if (lane == 0) {
    float m = acc[0];
    #pragma unroll
    for (int e = 1; e < 8; e++) m = fmaxf(m, acc[e]);
    float ex[8], s = 0.f;
    #pragma unroll
    for (int e = 0; e < 8; e++) { ex[e] = expf(acc[e] - m); s += ex[e]; }
    float raw[8];
    #pragma unroll
    for (int e = 0; e < 8; e++) raw[e] = ex[e] / s;
    float lse = m + logf(s);
    int b = t >> 9;
    #pragma unroll
    for (int e = 0; e < 8; e++) atomicAdd(&sum_raw[b * 8 + e], raw[e]);
    int e0 = 0;
    for (int e = 1; e < 8; e++) if (raw[e] > raw[e0]) e0 = e;
    int e1 = (e0 == 0) ? 1 : 0;
    for (int e = 0; e < 8; e++) if (e != e0 && raw[e] > raw[e1]) e1 = e;
    float gv0 = raw[e0], gv1 = raw[e1];
    float den = fmaxf(gv0 + gv1, 1e-9f);
    float g0 = gv0 / den, g1 = gv1 / den;
    uint32_t x0 = (uint32_t)t, x1 = (uint32_t)t + 1024u;
    threefry(fk0, fk1, x0, x1);
    union { uint32_t u; float f; } uf; uf.u = (x1 >> 9) | 0x3f800000u;
    float u = uf.f - 1.f;
    int r1 = (u < g1 * 5.f) ? 1 : 0;
    e0a[t] = e0; e1a[t] = e1; g0a[t] = g0; g1a[t] = g1; r1a[t] = r1;
    atomicAdd(&cnt1[b * 8 + e0], 1.f);
    atomicAdd(lse2, lse * lse);
  }
}

// capacity scan: LDS-staged serial per (b,e)
__global__ void k_scan(const int* __restrict__ e0a, const int* __restrict__ e1a,
                       const int* __restrict__ r1a,
                       int* __restrict__ s0a, int* __restrict__ s1a,
                       int* __restrict__ ts) {
  __shared__ int se0[NTOK], se1[NTOK], sr1[NTOK];
  int tid = threadIdx.x;
  for (int i = tid; i < NTOK; i += 64) {
    se0[i] = e0a[i]; se1[i] = e1a[i]; sr1[i] = r1a[i];
  }
  __syncthreads();
  if (tid >= 16) return;
  int b = tid >> 3, e = tid & 7;
  int base = (e * 2 + b) * CAP;
  for (int c = 0; c < CAP; c++) ts[base + c] = -1;
  int c0 = 0;
  for (int n = 0; n < SEQ; n++) {
    int t = b * SEQ + n;
    if (se0[t] == e) {
      if (c0 < CAP) { s0a[t] = c0; ts[base + c0] = t; } else s0a[t] = -1;
      c0++;
    }
  }
  int prev = c0 < CAP ? c0 : CAP;
  int c1 = 0;
  for (int n = 0; n < SEQ; n++) {
    int t = b * SEQ + n;
    if (se1[t] == e) {
      if (sr1[t]) {
        int pos = prev + c1;
        if (pos < CAP) { s1a[t] = pos; ts[base + pos] = t; } else s1a[t] = -1;
        c1++;
      } else s1a[t] = -1;
    }
  }
}

// dispatch f32 (fallback)
__global__ void k_dispatch(const float* __restrict__ RB, const int* __restrict__ ts,
                           float* __restrict__ EIN) {
  int s = blockIdx.x;
  int t = ts[s];
  #pragma unroll
  for (int i = 0; i < 3; i++) {
    int d = threadIdx.x + 256 * i;
    EIN[(long long)s * DD + d] = (t >= 0) ? RB[(long long)t * DD + d] : 0.f;
  }
}

// dispatch split planes
__global__ void k_dispatch_s(const unsigned short* __restrict__ RBh,
                             const unsigned short* __restrict__ RBl,
                             const int* __restrict__ ts,
                             unsigned short* __restrict__ Eh,
                             unsigned short* __restrict__ El) {
  int s = blockIdx.x;
  int t = ts[s];
  #pragma unroll
  for (int i = 0; i < 3; i++) {
    int d = threadIdx.x + 256 * i;
    long long o = (long long)s * DD + d;
    if (t >= 0) {
      long long src = (long long)t * DD + d;
      Eh[o] = RBh[src]; El[o] = RBl[src];
    } else {
      Eh[o] = 0; El[o] = 0;
    }
  }
}

__global__ void k_combine(const int* __restrict__ e0a, const int* __restrict__ e1a,
                          const int* __restrict__ s0a, const int* __restrict__ s1a,
                          const float* __restrict__ g0a, const float* __restrict__ g1a,
                          const float* __restrict__ EOUT, float* __restrict__ XM) {
  int t = blockIdx.x; int b = t >> 9;
  int s0 = s0a[t], s1 = s1a[t];
  long long r0 = ((long long)e0a[t] * 160 + b * CAP + s0) * DD;
  long long r1 = ((long long)e1a[t] * 160 + b * CAP + s1) * DD;
  float g0 = g0a[t], g1 = g1a[t];
  #pragma unroll
  for (int i = 0; i < 3; i++) {
    int d = threadIdx.x + 256 * i;
    float mo = 0.f;
    if (s0 >= 0) mo += g0 * EOUT[r0 + d];
    if (s1 >= 0) mo += g1 * EOUT[r1 + d];
    XM[(long long)t * DD + d] += mo;
  }
}

__global__ void k_aux(const float* __restrict__ sum_raw, const float* __restrict__ cnt1,
                      const float* __restrict__ lse2, float* __restrict__ aux) {
  if (threadIdx.x == 0 && blockIdx.x == 0) {
    float bal = 0.f;
    for (int i = 0; i < 16; i++) bal += sum_raw[i] * cnt1[i];
    bal *= 4.f / (512.f * 512.f);
    float zl = lse2[0] * (1.f / 1024.f);
    aux[0] += 0.01f * bal + 0.001f * zl;
  }
}

// ---------------- host ----------------
extern "C" void kernel_launch(void* const* d_in, const int* in_sizes, int n_in,
                              void* d_out, int out_size, void* d_ws, size_t ws_size,
                              hipStream_t stream) {
  const int*   ids  = (const int*)d_in[0];
  const float* wte  = (const float*)d_in[2];
  const float* wpe  = (const float*)d_in[3];
  const float* ln1g = (const float*)d_in[4];
  const float* ln1b = (const float*)d_in[5];
  const float* ln2g = (const float*)d_in[6];
  const float* ln2b = (const float*)d_in[7];
  const float* aqw  = (const float*)d_in[8];
  const float* aqb  = (const float*)d_in[9];
  const float* apw  = (const float*)d_in[10];
  const float* apb  = (const float*)d_in[11];
  const float* mfw  = (const float*)d_in[12];
  const float* mfb  = (const float*)d_in[13];
  const float* mpw  = (const float*)d_in[14];
  const float* mpb  = (const float*)d_in[15];
  const float* lnfg = (const float*)d_in[16];
  const float* lnfb = (const float*)d_in[17];
  const float* ffbng = (const float*)d_in[18];
  const float* ffbw1 = (const float*)d_in[19];
  const float* ffbb1 = (const float*)d_in[20];
  const float* ffbmb = (const float*)d_in[21];
  const float* ffbw2 = (const float*)d_in[22];
  const float* ffbb2 = (const float*)d_in[23];
  const float* ffang = (const float*)d_in[24];
  const float* ffaw1 = (const float*)d_in[25];
  const float* ffab1 = (const float*)d_in[26];
  const float* ffamb = (const float*)d_in[27];
  const float* ffaw2 = (const float*)d_in[28];
  const float* ffab2 = (const float*)d_in[29];
  const float* moeng = (const float*)d_in[30];
  const float* gw    = (const float*)d_in[31];
  const float* ew1   = (const float*)d_in[32];
  const float* eb1   = (const float*)d_in[33];
  const float* emb   = (const float*)d_in[34];
  const float* ew2   = (const float*)d_in[35];
  const float* eb2   = (const float*)d_in[36];

  float* ws = (float*)d_ws;
  float* X    = ws + 0;          // 786432
  float* LNf  = ws + 786432;     // 786432 (f32 norm out)
  float* RBf  = ws + 1572864;    // 786432 (f32 rms out)
  float* XM   = ws + 2359296;    // 786432
  float* QKV  = ws + 3145728;    // 2359296
  float* BIG  = ws + 5505024;    // 6291456
  float* GB   = ws + 11796480;   // 2621440
  float* EIN  = ws + 14417920;   // 983040
  float* EOUT = ws + 15400960;   // 983040
  float* MISC = ws + 16384000;
  int*   e0a = (int*)MISC;
  int*   e1a = e0a + 1024;
  int*   s0a = e1a + 1024;
  int*   s1a = s0a + 1024;
  int*   r1a = s1a + 1024;
  float* g0a = (float*)(r1a + 1024);
  float* g1a = g0a + 1024;
  int*   tsa = (int*)(g1a + 1024);
  float* sum_raw = (float*)(tsa + 1280);
  float* cnt1 = sum_raw + 16;
  float* lse2 = cnt1 + 16;

  // activation planes (time-share f32 regions; see dataflow audit in comments)
  unsigned short* LNh = (unsigned short*)(ws + 2359296);  // XM region (dead during attn/mlp use)
  unsigned short* LNl = LNh + 786432;
  unsigned short* Oh  = LNh;                              // attn O planes (after qkv consumed LN)
  unsigned short* Ol  = LNl;
  unsigned short* RBh = (unsigned short*)(ws + 3145728);  // QKV region (dead during moe)
  unsigned short* RBl = RBh + 786432;
  unsigned short* Hh  = (unsigned short*)(ws + 5505024);  // BIG region (scores dead during mlp)
  unsigned short* Hl  = Hh + 3145728;
  unsigned short* GBh = (unsigned short*)(ws + 11796480); // GB region (geglu out planes)
  unsigned short* GBl = GBh + 2621440;
  unsigned short* EINh = (unsigned short*)(ws + 14417920);
  unsigned short* EINl = EINh + 983040;

  float* logits = (float*)d_out;
  float* aux = logits + AUXOFF;

  // ---- pre-split weight region (shorts), after f32 region ----
  const long long E_wte = 38598144LL, E_qkv = 1769472LL, E_apr = 589824LL;
  const long long E_fc = 2359296LL, E_mpr = 2359296LL;
  const long long E_fb1 = 3145728LL, E_fb2 = 1572864LL;
  const long long E_ew1 = 3145728LL, E_ew2 = 1572864LL;
  const long long o_wte = 0;
  const long long o_qkv = o_wte + 2 * E_wte;
  const long long o_apr = o_qkv + 12 * E_qkv;
  const long long o_fc  = o_apr + 12 * E_apr;
  const long long o_mpr = o_fc  + 8 * E_fc;
  const long long o_fb1 = o_mpr + 8 * E_mpr;
  const long long o_fb2 = o_fb1 + 2 * E_fb1;
  const long long o_fa1 = o_fb2 + 2 * E_fb2;
  const long long o_fa2 = o_fa1 + 2 * E_fb1;
  const long long o_ew1 = o_fa2 + 2 * E_fb2;
  const long long o_ew2 = o_ew1 + 16 * E_ew1;
  const long long o_end = o_ew2 + 16 * E_ew2;
  unsigned short* SP = (unsigned short*)(ws + 16400000);
  const bool useSplit = ((long long)ws_size >= 16400000LL * 4 + o_end * 2);

  unsigned int fk[2][2];
  { uint32_t a = 0, b = 0; threefry(0u, 1234u, a, b); fk[0][0] = a; fk[0][1] = b; }
  { uint32_t a = 0, b = 3; threefry(0u, 1234u, a, b); fk[1][0] = a; fk[1][1] = b; }

  auto gemm = [&](bool transB, const float* A, const float* Bm, float* Cm,
                  unsigned short* Ch, unsigned short* Cl,
                  const float* bias, const float* resid,
                  int M, int N, int K, int lda, int ldb, int ldc,
                  int batches, int nh,
                  long long sAb, long long sAh, long long sBb, long long sBh,
                  long long sCb, long long sCh, long long sBias, int act, int osplit) {
    dim3 g((N + 63) / 64, (M + 63) / 64, batches);
    if (transB)
      k_gemm<true><<<g, 256, 0, stream>>>(A, Bm, Cm, Ch, Cl, bias, resid, M, N, K,
                                          lda, ldb, ldc, nh, sAb, sAh, sBb, sBh,
                                          sCb, sCh, sBias, act, osplit);
    else
      k_gemm<false><<<g, 256, 0, stream>>>(A, Bm, Cm, Ch, Cl, bias, resid, M, N, K,
                                           lda, ldb, ldc, nh, sAb, sAh, sBb, sBh,
                                           sCb, sCh, sBias, act, osplit);
  };

  // weight GEMM (split path): A planes, B planes; C f32 or planes
  auto wg = [&](const unsigned short* Ah_, const unsigned short* Al_,
                long long bOff, long long bE,
                float* Cf, unsigned short* Ch, unsigned short* Cl,
                const float* bias, const float* resid,
                int M, int N, int K, int ldc, int nz,
                long long sAz, long long sCz, long long sBias, int act, int swz) {
    dim3 g((N + 127) / 128, (M + 63) / 64, nz);
    k_gemmw<<<g, 256, 0, stream>>>(Ah_, Al_, SP + bOff, SP + bOff + bE, Cf, Ch, Cl,
                                   bias, resid, M, N, K, ldc, sAz, 2 * bE, sCz,
                                   sBias, act, swz);
  };

  k_zero<<<1, 64, 0, stream>>>(aux, 1);
  k_embed<<<1024, 256, 0, stream>>>(ids, wte, wpe, X);

  if (useSplit) {
    auto splitT = [&](const float* src, long long dOff, long long E, int K_, int N_,
                      int nz, long long sSrc) {
      k_split_t<<<dim3(N_ / 32, K_ / 32, nz), 256, 0, stream>>>(
          src, SP + dOff, SP + dOff + E, K_, N_, sSrc, 2 * E);
    };
    k_split<<<(int)((E_wte / 4 + 255) / 256), 256, 0, stream>>>(
        wte, SP + o_wte, SP + o_wte + E_wte, E_wte);
    splitT(aqw, o_qkv, E_qkv, 768, 2304, 6, 768LL * 2304);
    splitT(apw, o_apr, E_apr, 768, 768, 6, 768LL * 768);
    int mlpLayers[4] = {1, 2, 4, 5};
    for (int s = 0; s < 4; s++) {
      int L = mlpLayers[s];
      splitT(mfw + (long long)L * E_fc,  o_fc  + s * 2 * E_fc,  E_fc,  768, 3072, 1, 0);
      splitT(mpw + (long long)L * E_mpr, o_mpr + s * 2 * E_mpr, E_mpr, 3072, 768, 1, 0);
    }
    splitT(ffbw1, o_fb1, E_fb1, 768, 4096, 1, 0);
    splitT(ffbw2, o_fb2, E_fb2, 2048, 768, 1, 0);
    splitT(ffaw1, o_fa1, E_fb1, 768, 4096, 1, 0);
    splitT(ffaw2, o_fa2, E_fb2, 2048, 768, 1, 0);
    splitT(ew1, o_ew1, E_ew1, 768, 4096, 8, (long long)768 * 4096);
    splitT(ew2, o_ew2, E_ew2, 2048, 768, 8, (long long)2048 * 768);

    auto moe = [&](unsigned int fk0, unsigned int fk1) {
      k_rmsnorm<<<1024, 64, 0, stream>>>(LNf, ffbng, RBf, RBh, RBl);
      wg(RBh, RBl, o_fb1, E_fb1, BIG, nullptr, nullptr, ffbb1, nullptr,
         1024, 4096, 768, 4096, 1, 0, 0, 0, 0, 1);
      k_geglu<<<1024, 256, 0, stream>>>(BIG, ffbmb, nullptr, GBh, GBl, 1024);
      wg(GBh, GBl, o_fb2, E_fb2, XM, nullptr, nullptr, ffbb2, LNf,
         1024, 768, 2048, 768, 1, 0, 0, 0, 0, 1);
      k_rmsnorm<<<1024, 64, 0, stream>>>(XM, moeng, RBf, RBh, RBl);
      k_zero<<<1, 64, 0, stream>>>(sum_raw, 33);
      k_gate<<<1024, 64, 0, stream>>>(RBf, gw, fk0, fk1, e0a, e1a, g0a, g1a, r1a,
                                      sum_raw, cnt1, lse2);
      k_scan<<<1, 64, 0, stream>>>(e0a, e1a, r1a, s0a, s1a, tsa);
      k_dispatch_s<<<1280, 256, 0, stream>>>(RBh, RBl, tsa, EINh, EINl);
      wg(EINh, EINl, o_ew1, E_ew1, BIG, nullptr, nullptr, eb1, nullptr,
         160, 4096, 768, 4096, 8, 122880, 655360, 4096, 0, 0);
      k_geglu<<<1280, 256, 0, stream>>>(BIG, emb, nullptr, GBh, GBl, 160);
      wg(GBh, GBl, o_ew2, E_ew2, EOUT, nullptr, nullptr, eb2, nullptr,
         160, 768, 2048, 768, 8, 327680, 122880, 768, 0, 0);
      k_combine<<<1024, 256, 0, stream>>>(e0a, e1a, s0a, s1a, g0a, g1a, EOUT, XM);
      k_aux<<<1, 1, 0, stream>>>(sum_raw, cnt1, lse2, aux);
      k_rmsnorm<<<1024, 64, 0, stream>>>(XM, ffang, RBf, RBh, RBl);
      wg(RBh, RBl, o_fa1, E_fb1, BIG, nullptr, nullptr, ffab1, nullptr,
         1024, 4096, 768, 4096, 1, 0, 0, 0, 0, 1);
      k_geglu<<<1024, 256, 0, stream>>>(BIG, ffamb, nullptr, GBh, GBl, 1024);
      wg(GBh, GBl, o_fa2, E_fb2, XM, nullptr, nullptr, ffab2, XM,
         1024, 768, 2048, 768, 1, 0, 0, 0, 0, 1);
      k_add<<<3072, 256, 0, stream>>>(X, XM, 786432);
    };

    for (int i = 0; i < 6; i++) {
      k_layernorm<<<1024, 64, 0, stream>>>(X, ln1g + i * 768, ln1b + i * 768, LNf, LNh, LNl);
      wg(LNh, LNl, o_qkv + (long long)i * 2 * E_qkv, E_qkv, QKV, nullptr, nullptr,
         aqb + (long long)i * 2304, nullptr, 1024, 2304, 768, 2304, 1, 0, 0, 0, 0, 1);
      gemm(true, QKV, QKV + 768, BIG, nullptr, nullptr, nullptr, nullptr,
           512, 512, 64, 2304, 2304, 512, 24, 12,
           1179648, 64, 1179648, 64, 3145728, 262144, 0, 0, 0);
      k_softmax<<<12288, 64, 0, stream>>>(BIG);
      // PV -> O planes (time-share LN plane buffer; LN already consumed by qkv)
      gemm(false, BIG, QKV + 1536, nullptr, Oh, Ol, nullptr, nullptr,
           512, 64, 512, 512, 2304, 768, 24, 12,
           3145728, 262144, 1179648, 64, 393216, 64, 0, 0, 1);
      wg(Oh, Ol, o_apr + (long long)i * 2 * E_apr, E_apr, X, nullptr, nullptr,
         apb + (long long)i * 768, X, 1024, 768, 768, 768, 1, 0, 0, 0, 0, 1);
      k_layernorm<<<1024, 64, 0, stream>>>(X, ln2g + i * 768, ln2b + i * 768, LNf, LNh, LNl);
      if (i == 0 || i == 3) {
        moe(fk[i == 0 ? 0 : 1][0], fk[i == 0 ? 0 : 1][1]);
      } else {
        int slot = (i < 3) ? (i - 1) : (i - 2);
        // fc: gelu in epilogue, write split H planes (BIG region; scores dead)
        wg(LNh, LNl, o_fc + (long long)slot * 2 * E_fc, E_fc, nullptr, Hh, Hl,
           mfb + (long long)i * 3072, nullptr, 1024, 3072, 768, 3072, 1, 0, 0, 0, 1, 1);
        wg(Hh, Hl, o_mpr + (long long)slot * 2 * E_mpr, E_mpr, X, nullptr, nullptr,
           mpb + (long long)i * 768, X, 1024, 768, 3072, 768, 1, 0, 0, 0, 0, 1);
      }
    }

    k_layernorm<<<1024, 64, 0, stream>>>(X, lnfg, lnfb, LNf, LNh, LNl);
    wg(LNh, LNl, o_wte, E_wte, logits, nullptr, nullptr, nullptr, nullptr,
       1024, VOCAB, 768, VOCAB, 1, 0, 0, 0, 0, 1);
  } else {
    // -------- fallback: round-3 flow (f32 everywhere, in-kernel split) --------
    auto moe = [&](unsigned int fk0, unsigned int fk1) {
      k_rmsnorm<<<1024, 64, 0, stream>>>(LNf, ffbng, RBf, nullptr, nullptr);
      gemm(false, RBf, ffbw1, BIG, nullptr, nullptr, ffbb1, nullptr, 1024, 4096, 768,
           768, 4096, 4096, 1, 1, 0, 0, 0, 0, 0, 0, 0, 0, 0);
      k_geglu<<<1024, 256, 0, stream>>>(BIG, ffbmb, GB, nullptr, nullptr, 1024);
      gemm(false, GB, ffbw2, XM, nullptr, nullptr, ffbb2, LNf, 1024, 768, 2048,
           2048, 768, 768, 1, 1, 0, 0, 0, 0, 0, 0, 0, 0, 0);
      k_rmsnorm<<<1024, 64, 0, stream>>>(XM, moeng, RBf, nullptr, nullptr);
      k_zero<<<1, 64, 0, stream>>>(sum_raw, 33);
      k_gate<<<1024, 64, 0, stream>>>(RBf, gw, fk0, fk1, e0a, e1a, g0a, g1a, r1a,
                                      sum_raw, cnt1, lse2);
      k_scan<<<1, 64, 0, stream>>>(e0a, e1a, r1a, s0a, s1a, tsa);
      k_dispatch<<<1280, 256, 0, stream>>>(RBf, tsa, EIN);
      gemm(false, EIN, ew1, BIG, nullptr, nullptr, eb1, nullptr, 160, 4096, 768,
           768, 4096, 4096, 8, 1, 122880, 0, 3145728, 0, 655360, 0, 4096, 0, 0);
      k_geglu<<<1280, 256, 0, stream>>>(BIG, emb, GB, nullptr, nullptr, 160);
      gemm(false, GB, ew2, EOUT, nullptr, nullptr, eb2, nullptr, 160, 768, 2048,
           2048, 768, 768, 8, 1, 327680, 0, 1572864, 0, 122880, 0, 768, 0, 0);
      k_combine<<<1024, 256, 0, stream>>>(e0a, e1a, s0a, s1a, g0a, g1a, EOUT, XM);
      k_aux<<<1, 1, 0, stream>>>(sum_raw, cnt1, lse2, aux);
      k_rmsnorm<<<1024, 64, 0, stream>>>(XM, ffang, RBf, nullptr, nullptr);
      gemm(false, RBf, ffaw1, BIG, nullptr, nullptr, ffab1, nullptr, 1024, 4096, 768,
           768, 4096, 4096, 1, 1, 0, 0, 0, 0, 0, 0, 0, 0, 0);
      k_geglu<<<1024, 256, 0, stream>>>(BIG, ffamb, GB, nullptr, nullptr, 1024);
      gemm(false, GB, ffaw2, XM, nullptr, nullptr, ffab2, XM, 1024, 768, 2048,
           2048, 768, 768, 1, 1, 0, 0, 0, 0, 0, 0, 0, 0, 0);
      k_add<<<3072, 256, 0, stream>>>(X, XM, 786432);
    };

    for (int i = 0; i < 6; i++) {
      k_layernorm<<<1024, 64, 0, stream>>>(X, ln1g + i * 768, ln1b + i * 768, LNf,
                                           nullptr, nullptr);
      gemm(false, LNf, aqw + (long long)i * 768 * 2304, QKV, nullptr, nullptr,
           aqb + (long long)i * 2304, nullptr, 1024, 2304, 768, 768, 2304, 2304,
           1, 1, 0, 0, 0, 0, 0, 0, 0, 0, 0);
      gemm(true, QKV, QKV + 768, BIG, nullptr, nullptr, nullptr, nullptr,
           512, 512, 64, 2304, 2304, 512, 24, 12,
           1179648, 64, 1179648, 64, 3145728, 262144, 0, 0, 0);
      k_softmax<<<12288, 64, 0, stream>>>(BIG);
      gemm(false, BIG, QKV + 1536, GB, nullptr, nullptr, nullptr, nullptr,
           512, 64, 512, 512, 2304, 768, 24, 12,
           3145728, 262144, 1179648, 64, 393216, 64, 0, 0, 0);
      gemm(false, GB, apw + (long long)i * 768 * 768, X, nullptr, nullptr,
           apb + (long long)i * 768, X, 1024, 768, 768, 768, 768, 768,
           1, 1, 0, 0, 0, 0, 0, 0, 0, 0, 0);
      k_layernorm<<<1024, 64, 0, stream>>>(X, ln2g + i * 768, ln2b + i * 768, LNf,
                                           nullptr, nullptr);
      if (i == 0 || i == 3) {
        moe(fk[i == 0 ? 0 : 1][0], fk[i == 0 ? 0 : 1][1]);
      } else {
        gemm(false, LNf, mfw + (long long)i * 768 * 3072, BIG, nullptr, nullptr,
             mfb + (long long)i * 3072, nullptr, 1024, 3072, 768, 768, 3072, 3072,
             1, 1, 0, 0, 0, 0, 0, 0, 0, 1, 0);
        gemm(false, BIG, mpw + (long long)i * 3072 * 768, X, nullptr, nullptr,
             mpb + (long long)i * 768, X, 1024, 768, 3072, 3072, 768, 768,
             1, 1, 0, 0, 0, 0, 0, 0, 0, 0, 0);
      }
    }
    k_layernorm<<<1024, 64, 0, stream>>>(X, lnfg, lnfb, LNf, nullptr, nullptr);
    gemm(true, LNf, wte, logits, nullptr, nullptr, nullptr, nullptr,
         1024, VOCAB, 768, 768, 768, VOCAB, 1, 1, 0, 0, 0, 0, 0, 0, 0, 0, 0);
  }
}